// Round 2
// baseline (714.402 us; speedup 1.0000x reference)
//
#include <hip/hip_runtime.h>
#include <math.h>

#define NRES 4096
#define SS   128      // S
#define A0C  5
#define NPTSC 11
#define ATOT 16       // A = A0 + NPTS
#define LD   256      // L
#define PD   64       // P
#define HD   128      // 2P
#define SCH  64       // s-chunk
#define RPAD 68       // padded LDS row (floats) to break bank aliasing

__device__ __forceinline__ float gelu_f(float x){
    float x3 = x*x*x;
    return 0.5f*x*(1.0f + tanhf(0.79788456080286535588f*(x + 0.044715f*x3)));
}

struct __align__(16) SMem {
    float big[HD*RPAD];                         // rbf passes (128x64 used) then hidden_t
    union RB {
        struct { float dist[SCH*ATOT]; float dirt[48*RPAD]; } dd;
        float pairT[PD*RPAD];
    } rb;
    float loc[LD];
    float pl[NPTSC*3];
    float rot[9];
    float ca3[3];
    float posall[ATOT*3];
    float basev[PD];
    float gatev[PD];
    float wtype[7*PD];
    float smolpos[SCH*3];
    int   typef[SS];
    float maskf[SS];
    float lnsc[PD], lnof[PD];
    float b1v[HD], b2v[PD];
    float red[4*PD];
    float fin[PD];
    float cnt;
};

#define FMA4x4(av, bv, A) do { \
    A[0][0] += av.x*bv.x; A[0][1] += av.x*bv.y; A[0][2] += av.x*bv.z; A[0][3] += av.x*bv.w; \
    A[1][0] += av.y*bv.x; A[1][1] += av.y*bv.y; A[1][2] += av.y*bv.z; A[1][3] += av.y*bv.w; \
    A[2][0] += av.z*bv.x; A[2][1] += av.z*bv.y; A[2][2] += av.z*bv.z; A[2][3] += av.z*bv.w; \
    A[3][0] += av.w*bv.x; A[3][1] += av.w*bv.y; A[3][2] += av.w*bv.z; A[3][3] += av.w*bv.w; \
} while(0)

__global__ __launch_bounds__(256, 2)
void smol_fused(const float* __restrict__ g_local,
                const float* __restrict__ g_pos,
                const int*   __restrict__ g_type,
                const float* __restrict__ g_spos,
                const int*   __restrict__ g_mask,
                const float* __restrict__ w_points,
                const float* __restrict__ w_type,
                const float* __restrict__ w_local,
                const float* __restrict__ w_dir,
                const float* __restrict__ w_dist,
                const float* __restrict__ ln_scale,
                const float* __restrict__ ln_offset,
                const float* __restrict__ w_mlp1,
                const float* __restrict__ b_mlp1,
                const float* __restrict__ w_mlp2,
                const float* __restrict__ b_mlp2,
                const float* __restrict__ w_gate,
                const float* __restrict__ w_out,
                float* __restrict__ g_out)
{
    __shared__ SMem sm;
    const int n   = blockIdx.x;
    const int tid = threadIdx.x;
    const int ts  = tid >> 4, tp = tid & 15;
    const int s0  = ts * 4,  p0 = tp * 4;

    // ---------- phase 1: stage per-n data + small weights ----------
    sm.loc[tid] = g_local[n*LD + tid];
    // w_type is 7*64 = 448 floats > 256 threads: stage in two strided steps.
    // (BUG FIX r1: previous `if (tid < 448)` left rows 256..447 uninitialized LDS.)
    sm.wtype[tid] = w_type[tid];
    if (tid < 7*PD - 256) sm.wtype[256 + tid] = w_type[256 + tid];
    if (tid < PD){ sm.lnsc[tid] = ln_scale[tid]; sm.lnof[tid] = ln_offset[tid]; sm.b2v[tid] = b_mlp2[tid]; }
    if (tid < HD)  sm.b1v[tid] = b_mlp1[tid];
    if (tid < SS){ sm.typef[tid] = g_type[n*SS + tid];
                   sm.maskf[tid] = (g_mask[n*SS + tid] != 0) ? 1.0f : 0.0f; }
    if (tid >= 128 && tid < 128 + A0C*3) sm.posall[tid-128] = g_pos[n*A0C*3 + (tid-128)];
    __syncthreads();

    // ---------- phase 2: per-n precompute (frames, p_local, base, gate, count) ----------
    if (tid < 33){
        float a = 0.f;
        for (int i = 0; i < LD; ++i) a += sm.loc[i] * w_points[i*33 + tid];
        sm.pl[tid] = a;
    } else if (tid >= 64 && tid < 128){
        int p = tid - 64; float a = 0.f;
        for (int i = 0; i < LD; ++i) a += sm.loc[i] * w_local[i*PD + p];
        sm.basev[p] = a;
    } else if (tid >= 128 && tid < 192){
        int p = tid - 128; float a = 0.f;
        for (int i = 0; i < LD; ++i) a += sm.loc[i] * w_gate[i*PD + p];
        sm.gatev[p] = gelu_f(a);
    } else if (tid == 255){
        float nx=sm.posall[0], ny=sm.posall[1], nz=sm.posall[2];
        float cax=sm.posall[3], cay=sm.posall[4], caz=sm.posall[5];
        float cx=sm.posall[6], cy=sm.posall[7], cz=sm.posall[8];
        float v1x=cx-cax, v1y=cy-cay, v1z=cz-caz;
        float r = 1.0f/sqrtf(v1x*v1x + v1y*v1y + v1z*v1z + 1e-6f);
        float e1x=v1x*r, e1y=v1y*r, e1z=v1z*r;
        float v2x=nx-cax, v2y=ny-cay, v2z=nz-caz;
        float dp = e1x*v2x + e1y*v2y + e1z*v2z;
        float u2x=v2x-e1x*dp, u2y=v2y-e1y*dp, u2z=v2z-e1z*dp;
        r = 1.0f/sqrtf(u2x*u2x + u2y*u2y + u2z*u2z + 1e-6f);
        float e2x=u2x*r, e2y=u2y*r, e2z=u2z*r;
        float e3x=e1y*e2z-e1z*e2y, e3y=e1z*e2x-e1x*e2z, e3z=e1x*e2y-e1y*e2x;
        sm.rot[0]=e1x; sm.rot[1]=e2x; sm.rot[2]=e3x;
        sm.rot[3]=e1y; sm.rot[4]=e2y; sm.rot[5]=e3y;
        sm.rot[6]=e1z; sm.rot[7]=e2z; sm.rot[8]=e3z;
        sm.ca3[0]=cax; sm.ca3[1]=cay; sm.ca3[2]=caz;
    } else if (tid == 254){
        float c = 0.f;
        for (int s = 0; s < SS; ++s) c += sm.maskf[s];
        sm.cnt = c;
    }
    __syncthreads();

    // pseudo atoms: pos_all[5..15]
    if (tid < 33){
        int k = tid / 3, i2 = tid - k*3;
        sm.posall[(A0C + k)*3 + i2] =
            sm.rot[i2*3+0]*sm.pl[k*3+0] + sm.rot[i2*3+1]*sm.pl[k*3+1] +
            sm.rot[i2*3+2]*sm.pl[k*3+2] + sm.ca3[i2];
    }
    __syncthreads();

    float pooled[4] = {0.f, 0.f, 0.f, 0.f};

    for (int c = 0; c < 2; ++c){
        const int sbase = c * SCH;

        // ---- stage smol_pos chunk ----
        if (tid < SCH*3) sm.smolpos[tid] = g_spos[(n*SS + sbase)*3 + tid];
        __syncthreads();

        // ---- dist + directions ----
        {
            int s  = tid >> 2;
            int ab = (tid & 3) * 4;
            float px = sm.smolpos[s*3+0], py = sm.smolpos[s*3+1], pz = sm.smolpos[s*3+2];
            #pragma unroll
            for (int aa = 0; aa < 4; ++aa){
                int a = ab + aa;
                float rx = px - sm.posall[a*3+0];
                float ry = py - sm.posall[a*3+1];
                float rz = pz - sm.posall[a*3+2];
                float d  = sqrtf(rx*rx + ry*ry + rz*rz + 1e-6f);
                sm.rb.dd.dist[s*ATOT + a] = d;
                float inv = 1.0f / d;
                sm.rb.dd.dirt[(a*3+0)*RPAD + s] = rx * inv;
                sm.rb.dd.dirt[(a*3+1)*RPAD + s] = ry * inv;
                sm.rb.dd.dirt[(a*3+2)*RPAD + s] = rz * inv;
            }
        }
        __syncthreads();

        float acc[4][4];
        #pragma unroll
        for (int i = 0; i < 4; ++i){
            #pragma unroll
            for (int j = 0; j < 4; ++j) acc[i][j] = 0.f;
        }

        // ---- distances @ w_dist, K=256 in two passes of 128 ----
        for (int pass = 0; pass < 2; ++pass){
            { // fill rbf_t[k][s] for k = pass*128 .. +128
                int kr = tid >> 1, half = tid & 1;
                int a  = pass*8 + (kr >> 4);
                float cen = 0.8f * (float)(kr & 15);
                const float inv_sg = 1.0f / 0.75f;
                float* row = &sm.big[kr*RPAD + half*32];
                const float* dcol = &sm.rb.dd.dist[half*32*ATOT + a];
                #pragma unroll
                for (int j = 0; j < 32; j += 4){
                    float4 v;
                    float z0 = (dcol[(j+0)*ATOT] - cen) * inv_sg;
                    float z1 = (dcol[(j+1)*ATOT] - cen) * inv_sg;
                    float z2 = (dcol[(j+2)*ATOT] - cen) * inv_sg;
                    float z3 = (dcol[(j+3)*ATOT] - cen) * inv_sg;
                    v.x = __expf(-z0*z0); v.y = __expf(-z1*z1);
                    v.z = __expf(-z2*z2); v.w = __expf(-z3*z3);
                    *(float4*)&row[j] = v;
                }
            }
            __syncthreads();
            const float* wd = w_dist + pass*128*PD;
            #pragma unroll 4
            for (int k = 0; k < 128; ++k){
                float4 av = *(const float4*)&sm.big[k*RPAD + s0];
                float4 bv = *(const float4*)&wd[k*PD + p0];
                FMA4x4(av, bv, acc);
            }
            __syncthreads();
        }

        // ---- directions @ w_dir, K=48 ----
        #pragma unroll 4
        for (int k = 0; k < 48; ++k){
            float4 av = *(const float4*)&sm.rb.dd.dirt[k*RPAD + s0];
            float4 bv = *(const float4*)&w_dir[k*PD + p0];
            FMA4x4(av, bv, acc);
        }

        // ---- + w_type[type] + base ----
        #pragma unroll
        for (int i = 0; i < 4; ++i){
            int ty = sm.typef[sbase + s0 + i];
            const float* wt = &sm.wtype[ty*PD + p0];
            #pragma unroll
            for (int j = 0; j < 4; ++j) acc[i][j] += wt[j] + sm.basev[p0 + j];
        }

        // ---- LayerNorm over P per s-row (16 tp-lanes per row) ----
        #pragma unroll
        for (int i = 0; i < 4; ++i){
            float ssum = acc[i][0] + acc[i][1] + acc[i][2] + acc[i][3];
            ssum += __shfl_xor(ssum, 1);  ssum += __shfl_xor(ssum, 2);
            ssum += __shfl_xor(ssum, 4);  ssum += __shfl_xor(ssum, 8);
            float mu = ssum * (1.0f/64.0f);
            float d0 = acc[i][0]-mu, d1 = acc[i][1]-mu, d2 = acc[i][2]-mu, d3 = acc[i][3]-mu;
            float sq = d0*d0 + d1*d1 + d2*d2 + d3*d3;
            sq += __shfl_xor(sq, 1);  sq += __shfl_xor(sq, 2);
            sq += __shfl_xor(sq, 4);  sq += __shfl_xor(sq, 8);
            float inv = 1.0f / sqrtf(sq*(1.0f/64.0f) + 1e-5f);
            acc[i][0] = d0*inv*sm.lnsc[p0+0] + sm.lnof[p0+0];
            acc[i][1] = d1*inv*sm.lnsc[p0+1] + sm.lnof[p0+1];
            acc[i][2] = d2*inv*sm.lnsc[p0+2] + sm.lnof[p0+2];
            acc[i][3] = d3*inv*sm.lnsc[p0+3] + sm.lnof[p0+3];
        }
        __syncthreads();   // all dirt reads done before pairT overwrites the union

        // ---- write pair_t[p][s] ----
        #pragma unroll
        for (int j = 0; j < 4; ++j){
            float4 v = make_float4(acc[0][j], acc[1][j], acc[2][j], acc[3][j]);
            *(float4*)&sm.rb.pairT[(p0 + j)*RPAD + s0] = v;
        }
        __syncthreads();

        // ---- MLP1: hidden[s][h] = gelu(pair @ w_mlp1 + b1), 4s x 8h per thread ----
        {
            int h0 = tp * 8;
            float h[4][8];
            #pragma unroll
            for (int i = 0; i < 4; ++i){
                #pragma unroll
                for (int j = 0; j < 8; ++j) h[i][j] = 0.f;
            }
            #pragma unroll 2
            for (int k = 0; k < PD; ++k){
                float4 av  = *(const float4*)&sm.rb.pairT[k*RPAD + s0];
                float4 b0v = *(const float4*)&w_mlp1[k*HD + h0];
                float4 b1w = *(const float4*)&w_mlp1[k*HD + h0 + 4];
                h[0][0]+=av.x*b0v.x; h[0][1]+=av.x*b0v.y; h[0][2]+=av.x*b0v.z; h[0][3]+=av.x*b0v.w;
                h[0][4]+=av.x*b1w.x; h[0][5]+=av.x*b1w.y; h[0][6]+=av.x*b1w.z; h[0][7]+=av.x*b1w.w;
                h[1][0]+=av.y*b0v.x; h[1][1]+=av.y*b0v.y; h[1][2]+=av.y*b0v.z; h[1][3]+=av.y*b0v.w;
                h[1][4]+=av.y*b1w.x; h[1][5]+=av.y*b1w.y; h[1][6]+=av.y*b1w.z; h[1][7]+=av.y*b1w.w;
                h[2][0]+=av.z*b0v.x; h[2][1]+=av.z*b0v.y; h[2][2]+=av.z*b0v.z; h[2][3]+=av.z*b0v.w;
                h[2][4]+=av.z*b1w.x; h[2][5]+=av.z*b1w.y; h[2][6]+=av.z*b1w.z; h[2][7]+=av.z*b1w.w;
                h[3][0]+=av.w*b0v.x; h[3][1]+=av.w*b0v.y; h[3][2]+=av.w*b0v.z; h[3][3]+=av.w*b0v.w;
                h[3][4]+=av.w*b1w.x; h[3][5]+=av.w*b1w.y; h[3][6]+=av.w*b1w.z; h[3][7]+=av.w*b1w.w;
            }
            #pragma unroll
            for (int j = 0; j < 8; ++j){
                float bb = sm.b1v[h0 + j];
                float4 v = make_float4(gelu_f(h[0][j] + bb), gelu_f(h[1][j] + bb),
                                       gelu_f(h[2][j] + bb), gelu_f(h[3][j] + bb));
                *(float4*)&sm.big[(h0 + j)*RPAD + s0] = v;
            }
        }
        __syncthreads();

        // ---- MLP2: out3[s][p] = hidden @ w_mlp2 + b2; masked pooling ----
        {
            float o3[4][4];
            #pragma unroll
            for (int i = 0; i < 4; ++i){
                #pragma unroll
                for (int j = 0; j < 4; ++j) o3[i][j] = 0.f;
            }
            #pragma unroll 4
            for (int k = 0; k < HD; ++k){
                float4 av = *(const float4*)&sm.big[k*RPAD + s0];
                float4 bv = *(const float4*)&w_mlp2[k*PD + p0];
                FMA4x4(av, bv, o3);
            }
            #pragma unroll
            for (int i = 0; i < 4; ++i){
                float m = sm.maskf[sbase + s0 + i];
                if (m != 0.f){
                    #pragma unroll
                    for (int j = 0; j < 4; ++j) pooled[j] += o3[i][j] + sm.b2v[p0 + j];
                }
            }
        }
        __syncthreads();   // before next chunk reuses smolpos/dist/dirt/big
    }

    // ---- reduce pooled over the 16 ts-groups ----
    #pragma unroll
    for (int j = 0; j < 4; ++j){
        pooled[j] += __shfl_xor(pooled[j], 16);
        pooled[j] += __shfl_xor(pooled[j], 32);
    }
    {
        int wv = tid >> 6, lane = tid & 63;
        if (lane < 16){
            #pragma unroll
            for (int j = 0; j < 4; ++j) sm.red[wv*PD + tp*4 + j] = pooled[j];
        }
    }
    __syncthreads();
    if (tid < PD){
        float v = sm.red[tid] + sm.red[PD + tid] + sm.red[2*PD + tid] + sm.red[3*PD + tid];
        v = v / fmaxf(sm.cnt, 1.0f);
        sm.fin[tid] = sm.gatev[tid] * v;
    }
    __syncthreads();

    // ---- final: out[n][l] = fin @ w_out ----
    {
        float a = 0.f;
        #pragma unroll 4
        for (int p = 0; p < PD; ++p) a += sm.fin[p] * w_out[p*LD + tid];
        g_out[n*LD + tid] = a;
    }
}

extern "C" void kernel_launch(void* const* d_in, const int* in_sizes, int n_in,
                              void* d_out, int out_size, void* d_ws, size_t ws_size,
                              hipStream_t stream)
{
    (void)in_sizes; (void)n_in; (void)out_size; (void)d_ws; (void)ws_size;
    const float* g_local   = (const float*)d_in[0];
    const float* g_pos     = (const float*)d_in[1];
    const int*   g_type    = (const int*)  d_in[2];
    const float* g_spos    = (const float*)d_in[3];
    const int*   g_mask    = (const int*)  d_in[4];
    const float* w_points  = (const float*)d_in[5];
    const float* w_type    = (const float*)d_in[6];
    const float* w_local   = (const float*)d_in[7];
    const float* w_dir     = (const float*)d_in[8];
    const float* w_dist    = (const float*)d_in[9];
    const float* ln_scale  = (const float*)d_in[10];
    const float* ln_offset = (const float*)d_in[11];
    const float* w_mlp1    = (const float*)d_in[12];
    const float* b_mlp1    = (const float*)d_in[13];
    const float* w_mlp2    = (const float*)d_in[14];
    const float* b_mlp2    = (const float*)d_in[15];
    const float* w_gate    = (const float*)d_in[16];
    const float* w_out     = (const float*)d_in[17];

    smol_fused<<<dim3(NRES), dim3(256), 0, stream>>>(
        g_local, g_pos, g_type, g_spos, g_mask,
        w_points, w_type, w_local, w_dir, w_dist,
        ln_scale, ln_offset, w_mlp1, b_mlp1, w_mlp2, b_mlp2,
        w_gate, w_out, (float*)d_out);
}

// Round 3
// 576.193 us; speedup vs baseline: 1.2399x; 1.2399x over previous
//
#include <hip/hip_runtime.h>
#include <math.h>

#define NRES 4096
#define SS   128
#define A0C  5
#define ATOT 16
#define LD   256
#define PD   64
#define HD   128

typedef __attribute__((ext_vector_type(8))) short bf16x8;
typedef __attribute__((ext_vector_type(4))) float f32x4;

__device__ __forceinline__ unsigned short f2bf(float x){
    union { float f; unsigned int u; } v; v.f = x;
    unsigned int r = v.u + 0x7FFFu + ((v.u >> 16) & 1u);   // RNE to bf16
    return (unsigned short)(r >> 16);
}
__device__ __forceinline__ unsigned int packbf(float lo, float hi){
    return (unsigned int)f2bf(lo) | ((unsigned int)f2bf(hi) << 16);
}
__device__ __forceinline__ float gelu_f(float x){
    // x/(1+e^{-2t}), 2t = 1.59576912*(x + 0.044715 x^3)  == tanh-gelu exactly
    return x / (1.0f + __expf(-1.59576912f * x * (1.0f + 0.044715f * x * x)));
}
__device__ __forceinline__ f32x4 MFMA(bf16x8 a, bf16x8 b, f32x4 c){
    return __builtin_amdgcn_mfma_f32_16x16x32_bf16(a, b, c, 0, 0, 0);
}

// ---------------- prep: transpose+convert weights to bf16 in d_ws ----------------
// layout (ushort elements):
//   [0)      wsD   [64 n][256 k]   (w_dist^T)
//   [16384)  wsDir [64 n][64 k]    (w_dir^T, k>=48 zero)
//   [20480)  wsM1  [128 n][64 k]   (w_mlp1^T)
//   [28672)  wsM2  [64 n][128 k]   (w_mlp2^T)   total 36864 ushort = 73728 B
__global__ void smol_prep(const float* __restrict__ wdist, const float* __restrict__ wdir,
                          const float* __restrict__ wm1,  const float* __restrict__ wm2,
                          unsigned short* __restrict__ ws)
{
    int i = blockIdx.x * 256 + threadIdx.x;
    if (i < 16384){
        int nn = i >> 8, k = i & 255;
        ws[i] = f2bf(wdist[k*64 + nn]);
    } else if (i < 20480){
        int j = i - 16384; int nn = j >> 6, k = j & 63;
        ws[i] = (k < 48) ? f2bf(wdir[k*64 + nn]) : (unsigned short)0;
    } else if (i < 28672){
        int j = i - 20480; int nn = j >> 6, k = j & 63;
        ws[i] = f2bf(wm1[k*128 + nn]);
    } else if (i < 36864){
        int j = i - 28672; int nn = j >> 7, k = j & 127;
        ws[i] = f2bf(wm2[k*64 + nn]);
    }
}

// ---------------- main fused kernel ----------------
struct __align__(16) SMem {
    float  dist[64*17];       // [s][a], pad 17 (bank-spread)
    float  invd[64*17];
    unsigned short pairT[64*72];    // bf16 [s][k<=64], stride 72 (144B = 4 mod 32 words)
    unsigned short hidT[64*136];    // bf16 [s][k<=128], stride 136
    float  smolpos[64*3];
    float  loc[LD];
    float  posall3[ATOT*3];
    float  pl[33];
    float  rot[9];
    float  ca3[3];
    float  wtypef[7*PD];
    float  basev[PD];
    float  gatevv[PD];
    float  lnsc[PD], lnof[PD];
    float  b1v[HD], b2v[PD];
    int    typef[SS];
    float  maskf[SS];
    float  red[4*PD];
    float  fin[PD];
    float  cnt;
};

__global__ __launch_bounds__(256, 3)
void smol_fused(const float* __restrict__ g_local,
                const float* __restrict__ g_pos,
                const int*   __restrict__ g_type,
                const float* __restrict__ g_spos,
                const int*   __restrict__ g_mask,
                const float* __restrict__ w_points,
                const float* __restrict__ w_local,
                const float* __restrict__ w_type,
                const float* __restrict__ ln_scale,
                const float* __restrict__ ln_offset,
                const float* __restrict__ b_mlp1,
                const float* __restrict__ b_mlp2,
                const float* __restrict__ w_gate,
                const float* __restrict__ w_out,
                const unsigned short* __restrict__ ws,
                float* __restrict__ g_out)
{
    __shared__ SMem sm;
    const int n    = blockIdx.x;
    const int tid  = threadIdx.x;
    const int wv   = tid >> 6;        // wave 0..3 : owns rows 16wv..16wv+15
    const int lane = tid & 63;
    const int cB   = lane & 15;       // A-row / B-col selector
    const int g    = lane >> 4;       // k-subgroup 0..3
    const int m0   = wv * 16;
    const int sl   = m0 + cB;         // this lane's A row (chunk-local s)

    const unsigned short* wsD   = ws;
    const unsigned short* wsDir = ws + 16384;
    const unsigned short* wsM1  = ws + 20480;
    const unsigned short* wsM2  = ws + 28672;

    // ---------- stage ----------
    sm.loc[tid] = g_local[n*LD + tid];
    sm.wtypef[tid] = w_type[tid];
    if (tid < 7*PD - 256) sm.wtypef[256 + tid] = w_type[256 + tid];
    if (tid < PD){ sm.lnsc[tid] = ln_scale[tid]; sm.lnof[tid] = ln_offset[tid]; sm.b2v[tid] = b_mlp2[tid]; }
    if (tid < HD) sm.b1v[tid] = b_mlp1[tid];
    if (tid < SS){ sm.typef[tid] = g_type[n*SS + tid];
                   sm.maskf[tid] = (g_mask[n*SS + tid] != 0) ? 1.0f : 0.0f; }
    if (tid >= 128 && tid < 128 + A0C*3) sm.posall3[tid-128] = g_pos[n*A0C*3 + (tid-128)];
    __syncthreads();

    // ---------- per-n precompute ----------
    if (tid < 33){
        float a = 0.f;
        for (int i = 0; i < LD; ++i) a += sm.loc[i] * w_points[i*33 + tid];
        sm.pl[tid] = a;
    } else if (tid >= 64 && tid < 128){
        int p = tid - 64; float a = 0.f;
        for (int i = 0; i < LD; ++i) a += sm.loc[i] * w_local[i*PD + p];
        sm.basev[p] = a;
    } else if (tid >= 128 && tid < 192){
        int p = tid - 128; float a = 0.f;
        for (int i = 0; i < LD; ++i) a += sm.loc[i] * w_gate[i*PD + p];
        sm.gatevv[p] = gelu_f(a);
    } else if (tid == 255){
        float nx=sm.posall3[0], ny=sm.posall3[1], nz=sm.posall3[2];
        float cax=sm.posall3[3], cay=sm.posall3[4], caz=sm.posall3[5];
        float cx=sm.posall3[6], cy=sm.posall3[7], cz=sm.posall3[8];
        float v1x=cx-cax, v1y=cy-cay, v1z=cz-caz;
        float r = 1.0f/sqrtf(v1x*v1x + v1y*v1y + v1z*v1z + 1e-6f);
        float e1x=v1x*r, e1y=v1y*r, e1z=v1z*r;
        float v2x=nx-cax, v2y=ny-cay, v2z=nz-caz;
        float dp = e1x*v2x + e1y*v2y + e1z*v2z;
        float u2x=v2x-e1x*dp, u2y=v2y-e1y*dp, u2z=v2z-e1z*dp;
        r = 1.0f/sqrtf(u2x*u2x + u2y*u2y + u2z*u2z + 1e-6f);
        float e2x=u2x*r, e2y=u2y*r, e2z=u2z*r;
        float e3x=e1y*e2z-e1z*e2y, e3y=e1z*e2x-e1x*e2z, e3z=e1x*e2y-e1y*e2x;
        sm.rot[0]=e1x; sm.rot[1]=e2x; sm.rot[2]=e3x;
        sm.rot[3]=e1y; sm.rot[4]=e2y; sm.rot[5]=e3y;
        sm.rot[6]=e1z; sm.rot[7]=e2z; sm.rot[8]=e3z;
        sm.ca3[0]=cax; sm.ca3[1]=cay; sm.ca3[2]=caz;
    } else if (tid == 254){
        float c = 0.f;
        for (int s = 0; s < SS; ++s) c += sm.maskf[s];
        sm.cnt = c;
    }
    __syncthreads();
    if (tid < 33){
        int k = tid / 3, i2 = tid - k*3;
        sm.posall3[(A0C + k)*3 + i2] =
            sm.rot[i2*3+0]*sm.pl[k*3+0] + sm.rot[i2*3+1]*sm.pl[k*3+1] +
            sm.rot[i2*3+2]*sm.pl[k*3+2] + sm.ca3[i2];
    }
    __syncthreads();

    // preload per-lane column constants
    float lnscv[4], lnofv[4], basevv[4], b1vv[8];
    #pragma unroll
    for (int nt = 0; nt < 4; ++nt){
        lnscv[nt] = sm.lnsc[cB + 16*nt];
        lnofv[nt] = sm.lnof[cB + 16*nt];
        basevv[nt] = sm.basev[cB + 16*nt];
    }
    #pragma unroll
    for (int t = 0; t < 8; ++t) b1vv[t] = sm.b1v[cB + 16*t];

    float pooled[4] = {0.f, 0.f, 0.f, 0.f};
    union Frag { bf16x8 v; unsigned int u[4]; };

    // ====== chunk loop: fully wave-local, NO barriers inside ======
    for (int ch = 0; ch < 2; ++ch){
        const int sbase = ch * 64;

        // smolpos rows for this wave
        if (lane < 48){
            int sr = m0 + lane/3, c3 = lane - 3*(lane/3);
            sm.smolpos[sr*3 + c3] = g_spos[(n*SS + sbase + sr)*3 + c3];
        }
        // dist + invd for this wave's 16 rows (lane: row cB, atoms g*4..+4)
        {
            float px = sm.smolpos[sl*3+0], py = sm.smolpos[sl*3+1], pz = sm.smolpos[sl*3+2];
            #pragma unroll
            for (int aa = 0; aa < 4; ++aa){
                int a = g*4 + aa;
                float rx = px - sm.posall3[a*3+0];
                float ry = py - sm.posall3[a*3+1];
                float rz = pz - sm.posall3[a*3+2];
                float d  = sqrtf(rx*rx + ry*ry + rz*rz + 1e-6f);
                sm.dist[sl*17 + a] = d;
                sm.invd[sl*17 + a] = 1.0f / d;
            }
        }

        // ---- pair GEMM: dist-RBF (K=256) + dir (K=48 pad 64) ----
        f32x4 accP[4];
        #pragma unroll
        for (int nt = 0; nt < 4; ++nt) accP[nt] = f32x4{0.f,0.f,0.f,0.f};

        #pragma unroll 2
        for (int kk = 0; kk < 8; ++kk){
            // A-frag: 8 RBF bins of atom (2kk + g>>1), bins (g&1)*8..+8, row sl
            float d  = sm.dist[sl*17 + 2*kk + (lane>>5)];
            float dd = d * 1.33333333f;
            float b0f = (float)(((lane>>4)&1) * 8);
            Frag af;
            #pragma unroll
            for (int jj = 0; jj < 4; ++jj){
                float z0 = dd - 1.06666667f*(b0f + (float)(2*jj));
                float z1 = dd - 1.06666667f*(b0f + (float)(2*jj+1));
                af.u[jj] = packbf(__expf(-z0*z0), __expf(-z1*z1));
            }
            const unsigned short* bb = wsD + cB*256 + kk*32 + g*8;
            bf16x8 B0 = *(const bf16x8*)(bb);
            bf16x8 B1 = *(const bf16x8*)(bb + 16*256);
            bf16x8 B2 = *(const bf16x8*)(bb + 32*256);
            bf16x8 B3 = *(const bf16x8*)(bb + 48*256);
            accP[0] = MFMA(af.v, B0, accP[0]);
            accP[1] = MFMA(af.v, B1, accP[1]);
            accP[2] = MFMA(af.v, B2, accP[2]);
            accP[3] = MFMA(af.v, B3, accP[3]);
        }
        #pragma unroll
        for (int kk = 0; kk < 2; ++kk){
            int k0 = kk*32 + g*8;
            Frag af;
            if (k0 >= 48){
                af.u[0]=af.u[1]=af.u[2]=af.u[3]=0u;
            } else {
                float ev[8];
                #pragma unroll
                for (int j = 0; j < 8; ++j){
                    int k = k0 + j;
                    int a = (k * 21846) >> 16;     // k/3 for k<64
                    int cc = k - 3*a;
                    ev[j] = (sm.smolpos[sl*3+cc] - sm.posall3[a*3+cc]) * sm.invd[sl*17+a];
                }
                #pragma unroll
                for (int jj = 0; jj < 4; ++jj) af.u[jj] = packbf(ev[2*jj], ev[2*jj+1]);
            }
            const unsigned short* bb = wsDir + cB*64 + k0;
            bf16x8 B0 = *(const bf16x8*)(bb);
            bf16x8 B1 = *(const bf16x8*)(bb + 16*64);
            bf16x8 B2 = *(const bf16x8*)(bb + 32*64);
            bf16x8 B3 = *(const bf16x8*)(bb + 48*64);
            accP[0] = MFMA(af.v, B0, accP[0]);
            accP[1] = MFMA(af.v, B1, accP[1]);
            accP[2] = MFMA(af.v, B2, accP[2]);
            accP[3] = MFMA(af.v, B3, accP[3]);
        }

        // ---- epilogue: + base + wtype, LayerNorm, write pair' (bf16) ----
        #pragma unroll
        for (int r = 0; r < 3 + 1; ++r){
            int slr = m0 + g*4 + r;
            int ty  = sm.typef[sbase + slr];
            float v0 = accP[0][r] + basevv[0] + sm.wtypef[ty*PD + cB +  0];
            float v1 = accP[1][r] + basevv[1] + sm.wtypef[ty*PD + cB + 16];
            float v2 = accP[2][r] + basevv[2] + sm.wtypef[ty*PD + cB + 32];
            float v3 = accP[3][r] + basevv[3] + sm.wtypef[ty*PD + cB + 48];
            float ssum = v0+v1+v2+v3;
            ssum += __shfl_xor(ssum,1); ssum += __shfl_xor(ssum,2);
            ssum += __shfl_xor(ssum,4); ssum += __shfl_xor(ssum,8);
            float mu = ssum * (1.0f/64.0f);
            float d0=v0-mu, d1=v1-mu, d2=v2-mu, d3=v3-mu;
            float sq = d0*d0+d1*d1+d2*d2+d3*d3;
            sq += __shfl_xor(sq,1); sq += __shfl_xor(sq,2);
            sq += __shfl_xor(sq,4); sq += __shfl_xor(sq,8);
            float inv = 1.0f / sqrtf(sq*(1.0f/64.0f) + 1e-5f);
            float o0 = d0*inv*lnscv[0] + lnofv[0];
            float o1 = d1*inv*lnscv[1] + lnofv[1];
            float o2 = d2*inv*lnscv[2] + lnofv[2];
            float o3 = d3*inv*lnscv[3] + lnofv[3];
            float p0 = __shfl_xor(o0,1), p1 = __shfl_xor(o1,1);
            float p2 = __shfl_xor(o2,1), p3 = __shfl_xor(o3,1);
            unsigned int* pr = (unsigned int*)&sm.pairT[slr*72];
            if (!(lane & 1)){
                pr[(cB>>1) +  0] = packbf(o0, p0);
                pr[(cB>>1) +  8] = packbf(o1, p1);
            } else {
                pr[((cB-1)>>1) + 16] = packbf(p2, o2);
                pr[((cB-1)>>1) + 24] = packbf(p3, o3);
            }
        }

        // ---- MLP1 (K=64, N=128) ----
        f32x4 accH[8];
        #pragma unroll
        for (int t = 0; t < 8; ++t) accH[t] = f32x4{0.f,0.f,0.f,0.f};
        #pragma unroll
        for (int kk = 0; kk < 2; ++kk){
            bf16x8 a1 = *(const bf16x8*)&sm.pairT[(m0+cB)*72 + kk*32 + g*8];
            const unsigned short* bb = wsM1 + cB*64 + kk*32 + g*8;
            #pragma unroll
            for (int t = 0; t < 8; ++t){
                bf16x8 B = *(const bf16x8*)(bb + t*16*64);
                accH[t] = MFMA(a1, B, accH[t]);
            }
        }
        // gelu + write hidden (bf16)
        #pragma unroll
        for (int r = 0; r < 4; ++r){
            int slr = m0 + g*4 + r;
            float hv[8], hp[8];
            #pragma unroll
            for (int t = 0; t < 8; ++t) hv[t] = gelu_f(accH[t][r] + b1vv[t]);
            #pragma unroll
            for (int t = 0; t < 8; ++t) hp[t] = __shfl_xor(hv[t],1);
            unsigned int* hr = (unsigned int*)&sm.hidT[slr*136];
            if (!(lane & 1)){
                #pragma unroll
                for (int t = 0; t < 4; ++t) hr[(cB>>1) + 8*t] = packbf(hv[t], hp[t]);
            } else {
                #pragma unroll
                for (int t = 4; t < 8; ++t) hr[((cB-1)>>1) + 8*t] = packbf(hp[t], hv[t]);
            }
        }

        // ---- MLP2 (K=128, N=64) + masked pooling ----
        f32x4 accO[4];
        #pragma unroll
        for (int nt = 0; nt < 4; ++nt) accO[nt] = f32x4{0.f,0.f,0.f,0.f};
        #pragma unroll
        for (int kk = 0; kk < 4; ++kk){
            bf16x8 a2 = *(const bf16x8*)&sm.hidT[(m0+cB)*136 + kk*32 + g*8];
            const unsigned short* bb = wsM2 + cB*128 + kk*32 + g*8;
            #pragma unroll
            for (int nt = 0; nt < 4; ++nt){
                bf16x8 B = *(const bf16x8*)(bb + nt*16*128);
                accO[nt] = MFMA(a2, B, accO[nt]);
            }
        }
        #pragma unroll
        for (int r = 0; r < 4; ++r){
            float m = sm.maskf[sbase + m0 + g*4 + r];
            #pragma unroll
            for (int nt = 0; nt < 4; ++nt) pooled[nt] += m * accO[nt][r];
        }
    } // chunk loop

    // ---- reduce pooled: across g-groups (same col), then across waves ----
    #pragma unroll
    for (int nt = 0; nt < 4; ++nt){
        pooled[nt] += __shfl_xor(pooled[nt], 16);
        pooled[nt] += __shfl_xor(pooled[nt], 32);
    }
    if (g == 0){
        #pragma unroll
        for (int nt = 0; nt < 4; ++nt) sm.red[wv*PD + cB + 16*nt] = pooled[nt];
    }
    __syncthreads();
    if (tid < PD){
        float v = sm.red[tid] + sm.red[PD + tid] + sm.red[2*PD + tid] + sm.red[3*PD + tid];
        float mc = fmaxf(sm.cnt, 1.0f);
        v = (v + sm.cnt * sm.b2v[tid]) / mc;        // adds b2 exactly like ref (0 if cnt==0)
        sm.fin[tid] = sm.gatevv[tid] * v;
    }
    __syncthreads();
    {
        float a = 0.f;
        #pragma unroll 4
        for (int p = 0; p < PD; ++p) a += sm.fin[p] * w_out[p*LD + tid];
        g_out[n*LD + tid] = a;
    }
}

extern "C" void kernel_launch(void* const* d_in, const int* in_sizes, int n_in,
                              void* d_out, int out_size, void* d_ws, size_t ws_size,
                              hipStream_t stream)
{
    (void)in_sizes; (void)n_in; (void)out_size; (void)ws_size;
    const float* g_local   = (const float*)d_in[0];
    const float* g_pos     = (const float*)d_in[1];
    const int*   g_type    = (const int*)  d_in[2];
    const float* g_spos    = (const float*)d_in[3];
    const int*   g_mask    = (const int*)  d_in[4];
    const float* w_points  = (const float*)d_in[5];
    const float* w_type    = (const float*)d_in[6];
    const float* w_local   = (const float*)d_in[7];
    const float* w_dir     = (const float*)d_in[8];
    const float* w_dist    = (const float*)d_in[9];
    const float* ln_scale  = (const float*)d_in[10];
    const float* ln_offset = (const float*)d_in[11];
    const float* w_mlp1    = (const float*)d_in[12];
    const float* b_mlp1    = (const float*)d_in[13];
    const float* w_mlp2    = (const float*)d_in[14];
    const float* b_mlp2    = (const float*)d_in[15];
    const float* w_gate    = (const float*)d_in[16];
    const float* w_out     = (const float*)d_in[17];

    unsigned short* ws = (unsigned short*)d_ws;   // needs 73728 B

    smol_prep<<<dim3(144), dim3(256), 0, stream>>>(w_dist, w_dir, w_mlp1, w_mlp2, ws);

    smol_fused<<<dim3(NRES), dim3(256), 0, stream>>>(
        g_local, g_pos, g_type, g_spos, g_mask,
        w_points, w_local, w_type, ln_scale, ln_offset,
        b_mlp1, b_mlp2, w_gate, w_out, ws, (float*)d_out);
}

// Round 4
// 564.237 us; speedup vs baseline: 1.2661x; 1.0212x over previous
//
#include <hip/hip_runtime.h>
#include <math.h>

#define NRES 4096
#define SS   128
#define A0C  5
#define ATOT 16
#define LD   256
#define PD   64
#define HD   128

typedef __attribute__((ext_vector_type(8))) short bf16x8;
typedef __attribute__((ext_vector_type(4))) float f32x4;
typedef __attribute__((ext_vector_type(4))) unsigned int u32x4;

__device__ __forceinline__ unsigned short f2bf(float x){
    union { float f; unsigned int u; } v; v.f = x;
    unsigned int r = v.u + 0x7FFFu + ((v.u >> 16) & 1u);   // RNE to bf16
    return (unsigned short)(r >> 16);
}
__device__ __forceinline__ unsigned int packbf(float lo, float hi){
    return (unsigned int)f2bf(lo) | ((unsigned int)f2bf(hi) << 16);
}
__device__ __forceinline__ float gelu_f(float x){
    // x/(1+e^{-2t}), 2t = 1.59576912*(x + 0.044715 x^3)  == tanh-gelu exactly
    return x / (1.0f + __expf(-1.59576912f * x * (1.0f + 0.044715f * x * x)));
}
__device__ __forceinline__ f32x4 MFMA(bf16x8 a, bf16x8 b, f32x4 c){
    return __builtin_amdgcn_mfma_f32_16x16x32_bf16(a, b, c, 0, 0, 0);
}

// ---------------- prep: transpose+convert weights to bf16 in d_ws ----------------
// layout (ushort elements):
//   [0)      wsD   [64 n][256 k]   (w_dist^T)
//   [16384)  wsDir [64 n][64 k]    (w_dir^T, k>=48 zero)
//   [20480)  wsM1  [128 n][64 k]   (w_mlp1^T)
//   [28672)  wsM2  [64 n][128 k]   (w_mlp2^T)   total 36864 ushort = 73728 B
__global__ void smol_prep(const float* __restrict__ wdist, const float* __restrict__ wdir,
                          const float* __restrict__ wm1,  const float* __restrict__ wm2,
                          unsigned short* __restrict__ ws)
{
    int i = blockIdx.x * 256 + threadIdx.x;
    if (i < 16384){
        int nn = i >> 8, k = i & 255;
        ws[i] = f2bf(wdist[k*64 + nn]);
    } else if (i < 20480){
        int j = i - 16384; int nn = j >> 6, k = j & 63;
        ws[i] = (k < 48) ? f2bf(wdir[k*64 + nn]) : (unsigned short)0;
    } else if (i < 28672){
        int j = i - 20480; int nn = j >> 6, k = j & 63;
        ws[i] = f2bf(wm1[k*128 + nn]);
    } else if (i < 36864){
        int j = i - 28672; int nn = j >> 7, k = j & 127;
        ws[i] = f2bf(wm2[k*64 + nn]);
    }
}

// ---------------- main fused kernel ----------------
struct __align__(16) SMem {
    float  dist[64*17];       // [s][a], pad 17 (bank-spread)
    float  invd[64*17];
    unsigned short pairT[64*72];    // bf16 [s][k<=64], stride 72
    unsigned short hidT[64*136];    // bf16 [s][k<=128], stride 136
    float  smolpos[64*3];
    float  loc[LD];
    float  posall3[ATOT*3];
    float  pl[33];
    float  rot[9];
    float  ca3[3];
    float  wtypef[7*PD];
    float  basev[PD];
    float  gatevv[PD];
    float  lnsc[PD], lnof[PD];
    float  b1v[HD], b2v[PD];
    int    typef[SS];
    float  maskf[SS];
    float  red[4*PD];
    float  fin[PD];
    float  cnt;
};

__global__ __launch_bounds__(256, 3)
void smol_fused(const float* __restrict__ g_local,
                const float* __restrict__ g_pos,
                const int*   __restrict__ g_type,
                const float* __restrict__ g_spos,
                const int*   __restrict__ g_mask,
                const float* __restrict__ w_points,
                const float* __restrict__ w_local,
                const float* __restrict__ w_type,
                const float* __restrict__ ln_scale,
                const float* __restrict__ ln_offset,
                const float* __restrict__ b_mlp1,
                const float* __restrict__ b_mlp2,
                const float* __restrict__ w_gate,
                const float* __restrict__ w_out,
                const unsigned short* __restrict__ ws,
                float* __restrict__ g_out)
{
    __shared__ SMem sm;
    const int n    = blockIdx.x;
    const int tid  = threadIdx.x;
    const int wv   = tid >> 6;        // wave 0..3 : owns rows 16wv..16wv+15
    const int lane = tid & 63;
    const int cB   = lane & 15;       // A-row / B-col selector
    const int g    = lane >> 4;       // k-subgroup 0..3
    const int m0   = wv * 16;
    const int sl   = m0 + cB;         // this lane's A row (chunk-local s)

    const unsigned short* wsD   = ws;
    const unsigned short* wsDir = ws + 16384;
    const unsigned short* wsM1  = ws + 20480;
    const unsigned short* wsM2  = ws + 28672;

    // ---------- stage ----------
    sm.loc[tid] = g_local[n*LD + tid];
    sm.wtypef[tid] = w_type[tid];
    if (tid < 7*PD - 256) sm.wtypef[256 + tid] = w_type[256 + tid];
    if (tid < PD){ sm.lnsc[tid] = ln_scale[tid]; sm.lnof[tid] = ln_offset[tid]; sm.b2v[tid] = b_mlp2[tid]; }
    if (tid < HD) sm.b1v[tid] = b_mlp1[tid];
    if (tid < SS){ sm.typef[tid] = g_type[n*SS + tid];
                   sm.maskf[tid] = (g_mask[n*SS + tid] != 0) ? 1.0f : 0.0f; }
    if (tid >= 128 && tid < 128 + A0C*3) sm.posall3[tid-128] = g_pos[n*A0C*3 + (tid-128)];
    __syncthreads();

    // ---------- per-n precompute ----------
    if (tid < 33){
        float a = 0.f;
        for (int i = 0; i < LD; ++i) a += sm.loc[i] * w_points[i*33 + tid];
        sm.pl[tid] = a;
    } else if (tid >= 64 && tid < 128){
        int p = tid - 64; float a = 0.f;
        for (int i = 0; i < LD; ++i) a += sm.loc[i] * w_local[i*PD + p];
        sm.basev[p] = a;
    } else if (tid >= 128 && tid < 192){
        int p = tid - 128; float a = 0.f;
        for (int i = 0; i < LD; ++i) a += sm.loc[i] * w_gate[i*PD + p];
        sm.gatevv[p] = gelu_f(a);
    } else if (tid == 255){
        float nx=sm.posall3[0], ny=sm.posall3[1], nz=sm.posall3[2];
        float cax=sm.posall3[3], cay=sm.posall3[4], caz=sm.posall3[5];
        float cx=sm.posall3[6], cy=sm.posall3[7], cz=sm.posall3[8];
        float v1x=cx-cax, v1y=cy-cay, v1z=cz-caz;
        float r = 1.0f/sqrtf(v1x*v1x + v1y*v1y + v1z*v1z + 1e-6f);
        float e1x=v1x*r, e1y=v1y*r, e1z=v1z*r;
        float v2x=nx-cax, v2y=ny-cay, v2z=nz-caz;
        float dp = e1x*v2x + e1y*v2y + e1z*v2z;
        float u2x=v2x-e1x*dp, u2y=v2y-e1y*dp, u2z=v2z-e1z*dp;
        r = 1.0f/sqrtf(u2x*u2x + u2y*u2y + u2z*u2z + 1e-6f);
        float e2x=u2x*r, e2y=u2y*r, e2z=u2z*r;
        float e3x=e1y*e2z-e1z*e2y, e3y=e1z*e2x-e1x*e2z, e3z=e1x*e2y-e1y*e2x;
        sm.rot[0]=e1x; sm.rot[1]=e2x; sm.rot[2]=e3x;
        sm.rot[3]=e1y; sm.rot[4]=e2y; sm.rot[5]=e3y;
        sm.rot[6]=e1z; sm.rot[7]=e2z; sm.rot[8]=e3z;
        sm.ca3[0]=cax; sm.ca3[1]=cay; sm.ca3[2]=caz;
    } else if (tid == 254){
        float c = 0.f;
        for (int s = 0; s < SS; ++s) c += sm.maskf[s];
        sm.cnt = c;
    }
    __syncthreads();
    if (tid < 33){
        int k = tid / 3, i2 = tid - k*3;
        sm.posall3[(A0C + k)*3 + i2] =
            sm.rot[i2*3+0]*sm.pl[k*3+0] + sm.rot[i2*3+1]*sm.pl[k*3+1] +
            sm.rot[i2*3+2]*sm.pl[k*3+2] + sm.ca3[i2];
    }
    __syncthreads();

    // preload per-lane column constants
    float lnscv[4], lnofv[4], basevv[4], b1vv[8];
    #pragma unroll
    for (int nt = 0; nt < 4; ++nt){
        lnscv[nt] = sm.lnsc[cB + 16*nt];
        lnofv[nt] = sm.lnof[cB + 16*nt];
        basevv[nt] = sm.basev[cB + 16*nt];
    }
    #pragma unroll
    for (int t = 0; t < 8; ++t) b1vv[t] = sm.b1v[cB + 16*t];

    float pooled[4] = {0.f, 0.f, 0.f, 0.f};

    // ====== chunk loop: fully wave-local, NO barriers inside ======
    for (int ch = 0; ch < 2; ++ch){
        const int sbase = ch * 64;

        // smolpos rows for this wave
        if (lane < 48){
            int sr = m0 + lane/3, c3 = lane - 3*(lane/3);
            sm.smolpos[sr*3 + c3] = g_spos[(n*SS + sbase + sr)*3 + c3];
        }
        // dist + invd for this wave's 16 rows (lane: row cB, atoms g*4..+4)
        {
            float px = sm.smolpos[sl*3+0], py = sm.smolpos[sl*3+1], pz = sm.smolpos[sl*3+2];
            #pragma unroll
            for (int aa = 0; aa < 4; ++aa){
                int a = g*4 + aa;
                float rx = px - sm.posall3[a*3+0];
                float ry = py - sm.posall3[a*3+1];
                float rz = pz - sm.posall3[a*3+2];
                float d  = sqrtf(rx*rx + ry*ry + rz*rz + 1e-6f);
                sm.dist[sl*17 + a] = d;
                sm.invd[sl*17 + a] = 1.0f / d;
            }
        }

        // ---- pair GEMM: dist-RBF (K=256) + dir (K=48 pad 64) ----
        f32x4 accP[4];
        #pragma unroll
        for (int nt = 0; nt < 4; ++nt) accP[nt] = f32x4{0.f,0.f,0.f,0.f};

        #pragma unroll 2
        for (int kk = 0; kk < 8; ++kk){
            // A-frag: 8 RBF bins of atom (2kk + lane>>5), bins ((lane>>4)&1)*8..+8, row sl
            // Built entirely in registers (u32x4 + bit_cast). SCRATCH FIX r3:
            // the old union {bf16x8; uint[4]} was allocated to scratch ->
            // ~650 MB HBM write + read per dispatch.
            float d  = sm.dist[sl*17 + 2*kk + (lane>>5)];
            float dd = d * 1.33333333f;
            float b0f = (float)(((lane>>4)&1) * 8);
            float z0 = dd - 1.06666667f*(b0f + 0.f);
            float z1 = dd - 1.06666667f*(b0f + 1.f);
            float z2 = dd - 1.06666667f*(b0f + 2.f);
            float z3 = dd - 1.06666667f*(b0f + 3.f);
            float z4 = dd - 1.06666667f*(b0f + 4.f);
            float z5 = dd - 1.06666667f*(b0f + 5.f);
            float z6 = dd - 1.06666667f*(b0f + 6.f);
            float z7 = dd - 1.06666667f*(b0f + 7.f);
            u32x4 au;
            au.x = packbf(__expf(-z0*z0), __expf(-z1*z1));
            au.y = packbf(__expf(-z2*z2), __expf(-z3*z3));
            au.z = packbf(__expf(-z4*z4), __expf(-z5*z5));
            au.w = packbf(__expf(-z6*z6), __expf(-z7*z7));
            bf16x8 av = __builtin_bit_cast(bf16x8, au);

            const unsigned short* bb = wsD + cB*256 + kk*32 + g*8;
            bf16x8 B0 = *(const bf16x8*)(bb);
            bf16x8 B1 = *(const bf16x8*)(bb + 16*256);
            bf16x8 B2 = *(const bf16x8*)(bb + 32*256);
            bf16x8 B3 = *(const bf16x8*)(bb + 48*256);
            accP[0] = MFMA(av, B0, accP[0]);
            accP[1] = MFMA(av, B1, accP[1]);
            accP[2] = MFMA(av, B2, accP[2]);
            accP[3] = MFMA(av, B3, accP[3]);
        }
        #pragma unroll
        for (int kk = 0; kk < 2; ++kk){
            int k0 = kk*32 + g*8;
            u32x4 au;
            if (k0 >= 48){
                au.x = au.y = au.z = au.w = 0u;
            } else {
                #define DIRV(j) ({ int k_ = k0 + (j); int a_ = (k_*21846)>>16; int c_ = k_ - 3*a_; \
                                   (sm.smolpos[sl*3+c_] - sm.posall3[a_*3+c_]) * sm.invd[sl*17+a_]; })
                au.x = packbf(DIRV(0), DIRV(1));
                au.y = packbf(DIRV(2), DIRV(3));
                au.z = packbf(DIRV(4), DIRV(5));
                au.w = packbf(DIRV(6), DIRV(7));
                #undef DIRV
            }
            bf16x8 av = __builtin_bit_cast(bf16x8, au);
            const unsigned short* bb = wsDir + cB*64 + k0;
            bf16x8 B0 = *(const bf16x8*)(bb);
            bf16x8 B1 = *(const bf16x8*)(bb + 16*64);
            bf16x8 B2 = *(const bf16x8*)(bb + 32*64);
            bf16x8 B3 = *(const bf16x8*)(bb + 48*64);
            accP[0] = MFMA(av, B0, accP[0]);
            accP[1] = MFMA(av, B1, accP[1]);
            accP[2] = MFMA(av, B2, accP[2]);
            accP[3] = MFMA(av, B3, accP[3]);
        }

        // ---- epilogue: + base + wtype, LayerNorm, write pair' (bf16) ----
        #pragma unroll
        for (int r = 0; r < 4; ++r){
            int slr = m0 + g*4 + r;
            int ty  = sm.typef[sbase + slr];
            float v0 = accP[0][r] + basevv[0] + sm.wtypef[ty*PD + cB +  0];
            float v1 = accP[1][r] + basevv[1] + sm.wtypef[ty*PD + cB + 16];
            float v2 = accP[2][r] + basevv[2] + sm.wtypef[ty*PD + cB + 32];
            float v3 = accP[3][r] + basevv[3] + sm.wtypef[ty*PD + cB + 48];
            float ssum = v0+v1+v2+v3;
            ssum += __shfl_xor(ssum,1); ssum += __shfl_xor(ssum,2);
            ssum += __shfl_xor(ssum,4); ssum += __shfl_xor(ssum,8);
            float mu = ssum * (1.0f/64.0f);
            float d0=v0-mu, d1=v1-mu, d2=v2-mu, d3=v3-mu;
            float sq = d0*d0+d1*d1+d2*d2+d3*d3;
            sq += __shfl_xor(sq,1); sq += __shfl_xor(sq,2);
            sq += __shfl_xor(sq,4); sq += __shfl_xor(sq,8);
            float inv = 1.0f / sqrtf(sq*(1.0f/64.0f) + 1e-5f);
            float o0 = d0*inv*lnscv[0] + lnofv[0];
            float o1 = d1*inv*lnscv[1] + lnofv[1];
            float o2 = d2*inv*lnscv[2] + lnofv[2];
            float o3 = d3*inv*lnscv[3] + lnofv[3];
            float p0 = __shfl_xor(o0,1), p1 = __shfl_xor(o1,1);
            float p2 = __shfl_xor(o2,1), p3 = __shfl_xor(o3,1);
            unsigned int* pr = (unsigned int*)&sm.pairT[slr*72];
            if (!(lane & 1)){
                pr[(cB>>1) +  0] = packbf(o0, p0);
                pr[(cB>>1) +  8] = packbf(o1, p1);
            } else {
                pr[((cB-1)>>1) + 16] = packbf(p2, o2);
                pr[((cB-1)>>1) + 24] = packbf(p3, o3);
            }
        }

        // ---- MLP1 (K=64, N=128) ----
        f32x4 accH[8];
        #pragma unroll
        for (int t = 0; t < 8; ++t) accH[t] = f32x4{0.f,0.f,0.f,0.f};
        #pragma unroll
        for (int kk = 0; kk < 2; ++kk){
            bf16x8 a1 = *(const bf16x8*)&sm.pairT[(m0+cB)*72 + kk*32 + g*8];
            const unsigned short* bb = wsM1 + cB*64 + kk*32 + g*8;
            #pragma unroll
            for (int t = 0; t < 8; ++t){
                bf16x8 B = *(const bf16x8*)(bb + t*16*64);
                accH[t] = MFMA(a1, B, accH[t]);
            }
        }
        // gelu + write hidden (bf16)
        #pragma unroll
        for (int r = 0; r < 4; ++r){
            int slr = m0 + g*4 + r;
            float hv[8], hp[8];
            #pragma unroll
            for (int t = 0; t < 8; ++t) hv[t] = gelu_f(accH[t][r] + b1vv[t]);
            #pragma unroll
            for (int t = 0; t < 8; ++t) hp[t] = __shfl_xor(hv[t],1);
            unsigned int* hr = (unsigned int*)&sm.hidT[slr*136];
            if (!(lane & 1)){
                #pragma unroll
                for (int t = 0; t < 4; ++t) hr[(cB>>1) + 8*t] = packbf(hv[t], hp[t]);
            } else {
                #pragma unroll
                for (int t = 4; t < 8; ++t) hr[((cB-1)>>1) + 8*t] = packbf(hp[t], hv[t]);
            }
        }

        // ---- MLP2 (K=128, N=64) + masked pooling ----
        f32x4 accO[4];
        #pragma unroll
        for (int nt = 0; nt < 4; ++nt) accO[nt] = f32x4{0.f,0.f,0.f,0.f};
        #pragma unroll
        for (int kk = 0; kk < 4; ++kk){
            bf16x8 a2 = *(const bf16x8*)&sm.hidT[(m0+cB)*136 + kk*32 + g*8];
            const unsigned short* bb = wsM2 + cB*128 + kk*32 + g*8;
            #pragma unroll
            for (int nt = 0; nt < 4; ++nt){
                bf16x8 B = *(const bf16x8*)(bb + nt*16*128);
                accO[nt] = MFMA(a2, B, accO[nt]);
            }
        }
        #pragma unroll
        for (int r = 0; r < 4; ++r){
            float m = sm.maskf[sbase + m0 + g*4 + r];
            #pragma unroll
            for (int nt = 0; nt < 4; ++nt) pooled[nt] += m * accO[nt][r];
        }
    } // chunk loop

    // ---- reduce pooled: across g-groups (same col), then across waves ----
    #pragma unroll
    for (int nt = 0; nt < 4; ++nt){
        pooled[nt] += __shfl_xor(pooled[nt], 16);
        pooled[nt] += __shfl_xor(pooled[nt], 32);
    }
    if (g == 0){
        #pragma unroll
        for (int nt = 0; nt < 4; ++nt) sm.red[wv*PD + cB + 16*nt] = pooled[nt];
    }
    __syncthreads();
    if (tid < PD){
        float v = sm.red[tid] + sm.red[PD + tid] + sm.red[2*PD + tid] + sm.red[3*PD + tid];
        float mc = fmaxf(sm.cnt, 1.0f);
        v = (v + sm.cnt * sm.b2v[tid]) / mc;        // adds b2 exactly like ref (0 if cnt==0)
        sm.fin[tid] = sm.gatevv[tid] * v;
    }
    __syncthreads();
    {
        float a = 0.f;
        #pragma unroll 4
        for (int p = 0; p < PD; ++p) a += sm.fin[p] * w_out[p*LD + tid];
        g_out[n*LD + tid] = a;
    }
}

extern "C" void kernel_launch(void* const* d_in, const int* in_sizes, int n_in,
                              void* d_out, int out_size, void* d_ws, size_t ws_size,
                              hipStream_t stream)
{
    (void)in_sizes; (void)n_in; (void)out_size; (void)ws_size;
    const float* g_local   = (const float*)d_in[0];
    const float* g_pos     = (const float*)d_in[1];
    const int*   g_type    = (const int*)  d_in[2];
    const float* g_spos    = (const float*)d_in[3];
    const int*   g_mask    = (const int*)  d_in[4];
    const float* w_points  = (const float*)d_in[5];
    const float* w_type    = (const float*)d_in[6];
    const float* w_local   = (const float*)d_in[7];
    const float* w_dir     = (const float*)d_in[8];
    const float* w_dist    = (const float*)d_in[9];
    const float* ln_scale  = (const float*)d_in[10];
    const float* ln_offset = (const float*)d_in[11];
    const float* w_mlp1    = (const float*)d_in[12];
    const float* b_mlp1    = (const float*)d_in[13];
    const float* w_mlp2    = (const float*)d_in[14];
    const float* b_mlp2    = (const float*)d_in[15];
    const float* w_gate    = (const float*)d_in[16];
    const float* w_out     = (const float*)d_in[17];

    unsigned short* ws = (unsigned short*)d_ws;   // needs 73728 B

    smol_prep<<<dim3(144), dim3(256), 0, stream>>>(w_dist, w_dir, w_mlp1, w_mlp2, ws);

    smol_fused<<<dim3(NRES), dim3(256), 0, stream>>>(
        g_local, g_pos, g_type, g_spos, g_mask,
        w_points, w_local, w_type, ln_scale, ln_offset,
        b_mlp1, b_mlp2, w_gate, w_out, ws, (float*)d_out);
}

// Round 5
// 497.784 us; speedup vs baseline: 1.4352x; 1.1335x over previous
//
#include <hip/hip_runtime.h>
#include <math.h>

#define NRES 4096
#define SS   128
#define A0C  5
#define ATOT 16
#define LD   256
#define PD   64
#define HD   128

typedef __attribute__((ext_vector_type(8))) short bf16x8;
typedef __attribute__((ext_vector_type(4))) float f32x4;
typedef __attribute__((ext_vector_type(4))) unsigned int u32x4;

__device__ __forceinline__ unsigned short f2bf(float x){
    union { float f; unsigned int u; } v; v.f = x;
    unsigned int r = v.u + 0x7FFFu + ((v.u >> 16) & 1u);   // RNE to bf16
    return (unsigned short)(r >> 16);
}
__device__ __forceinline__ float gelu_f(float x){
    // x/(1+e^{-2t}), 2t = 1.59576912*(x + 0.044715 x^3)  == tanh-gelu exactly
    return x / (1.0f + __expf(-1.59576912f * x * (1.0f + 0.044715f * x * x)));
}
__device__ __forceinline__ f32x4 MFMA(bf16x8 a, bf16x8 b, f32x4 c){
    return __builtin_amdgcn_mfma_f32_16x16x32_bf16(a, b, c, 0, 0, 0);
}

// ---------------- prep: transpose+convert weights to bf16 in d_ws ----------------
// layout (ushort elements):
//   [0)      wsD   [64 n][256 k]   (w_dist^T)
//   [16384)  wsDir [64 n][64 k]    (w_dir^T, k>=48 zero)
//   [20480)  wsM1  [128 n][64 k]   (w_mlp1^T)
//   [28672)  wsM2  [64 n][128 k]   (w_mlp2^T)   total 36864 ushort = 73728 B
__global__ void smol_prep(const float* __restrict__ wdist, const float* __restrict__ wdir,
                          const float* __restrict__ wm1,  const float* __restrict__ wm2,
                          unsigned short* __restrict__ ws)
{
    int i = blockIdx.x * 256 + threadIdx.x;
    if (i < 16384){
        int nn = i >> 8, k = i & 255;
        ws[i] = f2bf(wdist[k*64 + nn]);
    } else if (i < 20480){
        int j = i - 16384; int nn = j >> 6, k = j & 63;
        ws[i] = (k < 48) ? f2bf(wdir[k*64 + nn]) : (unsigned short)0;
    } else if (i < 28672){
        int j = i - 20480; int nn = j >> 6, k = j & 63;
        ws[i] = f2bf(wm1[k*128 + nn]);
    } else if (i < 36864){
        int j = i - 28672; int nn = j >> 7, k = j & 127;
        ws[i] = f2bf(wm2[k*64 + nn]);
    }
}

// ---------------- main fused kernel ----------------
struct __align__(16) SMem {
    float  dist[64*17];             // [s][a], pad 17
    float  invd[64*17];
    unsigned short pairT[64*72];    // bf16 [s][k<=64], stride 72
    unsigned short hidT[64*136];    // bf16 [s][k<=128], stride 136
    float  smolpos[64*3];
    float  loc[LD];
    float  posall3[ATOT*3];
    float  pl[33];
    float  rot[9];
    float  ca3[3];
    float  wtypef[7*PD];
    float  basev[PD];
    float  gatevv[PD];
    float  lnsc[PD], lnof[PD];
    float  b1v[HD], b2v[PD];
    int    typef[SS];
    float  maskf[SS];
    float  red[4*PD];
    float  fin[PD];
    float  cnt;
};

__device__ __forceinline__ float dirv(const SMem& sm, int sl, int k){
    int a = (k * 21846) >> 16;      // k/3 for k<64
    int c = k - 3*a;
    return (sm.smolpos[sl*3+c] - sm.posall3[a*3+c]) * sm.invd[sl*17+a];
}

__global__ __launch_bounds__(256, 3)
void smol_fused(const float* __restrict__ g_local,
                const float* __restrict__ g_pos,
                const int*   __restrict__ g_type,
                const float* __restrict__ g_spos,
                const int*   __restrict__ g_mask,
                const float* __restrict__ w_points,
                const float* __restrict__ w_local,
                const float* __restrict__ w_type,
                const float* __restrict__ ln_scale,
                const float* __restrict__ ln_offset,
                const float* __restrict__ b_mlp1,
                const float* __restrict__ b_mlp2,
                const float* __restrict__ w_gate,
                const float* __restrict__ w_out,
                const unsigned short* __restrict__ ws,
                float* __restrict__ g_out)
{
    __shared__ SMem sm;
    const int n    = blockIdx.x;
    const int tid  = threadIdx.x;
    const int wv   = tid >> 6;        // wave 0..3 : owns rows 16wv..16wv+15
    const int lane = tid & 63;
    const int cB   = lane & 15;       // A-row / B-col selector
    const int g    = lane >> 4;       // k-subgroup 0..3
    const int m0   = wv * 16;
    const int sl   = m0 + cB;         // this lane's A row (chunk-local s)

    const unsigned short* wsD   = ws;
    const unsigned short* wsDir = ws + 16384;
    const unsigned short* wsM1  = ws + 20480;
    const unsigned short* wsM2  = ws + 28672;

    // ---------- stage ----------
    sm.loc[tid] = g_local[n*LD + tid];
    sm.wtypef[tid] = w_type[tid];
    if (tid < 7*PD - 256) sm.wtypef[256 + tid] = w_type[256 + tid];
    if (tid < PD){ sm.lnsc[tid] = ln_scale[tid]; sm.lnof[tid] = ln_offset[tid]; sm.b2v[tid] = b_mlp2[tid]; }
    if (tid < HD) sm.b1v[tid] = b_mlp1[tid];
    if (tid < SS){ sm.typef[tid] = g_type[n*SS + tid];
                   sm.maskf[tid] = (g_mask[n*SS + tid] != 0) ? 1.0f : 0.0f; }
    if (tid >= 128 && tid < 128 + A0C*3) sm.posall3[tid-128] = g_pos[n*A0C*3 + (tid-128)];
    __syncthreads();

    // ---------- per-n precompute ----------
    if (tid < 33){
        float a = 0.f;
        for (int i = 0; i < LD; ++i) a += sm.loc[i] * w_points[i*33 + tid];
        sm.pl[tid] = a;
    } else if (tid >= 64 && tid < 128){
        int p = tid - 64; float a = 0.f;
        for (int i = 0; i < LD; ++i) a += sm.loc[i] * w_local[i*PD + p];
        sm.basev[p] = a;
    } else if (tid >= 128 && tid < 192){
        int p = tid - 128; float a = 0.f;
        for (int i = 0; i < LD; ++i) a += sm.loc[i] * w_gate[i*PD + p];
        sm.gatevv[p] = gelu_f(a);
    } else if (tid == 255){
        float nx=sm.posall3[0], ny=sm.posall3[1], nz=sm.posall3[2];
        float cax=sm.posall3[3], cay=sm.posall3[4], caz=sm.posall3[5];
        float cx=sm.posall3[6], cy=sm.posall3[7], cz=sm.posall3[8];
        float v1x=cx-cax, v1y=cy-cay, v1z=cz-caz;
        float r = 1.0f/sqrtf(v1x*v1x + v1y*v1y + v1z*v1z + 1e-6f);
        float e1x=v1x*r, e1y=v1y*r, e1z=v1z*r;
        float v2x=nx-cax, v2y=ny-cay, v2z=nz-caz;
        float dp = e1x*v2x + e1y*v2y + e1z*v2z;
        float u2x=v2x-e1x*dp, u2y=v2y-e1y*dp, u2z=v2z-e1z*dp;
        r = 1.0f/sqrtf(u2x*u2x + u2y*u2y + u2z*u2z + 1e-6f);
        float e2x=u2x*r, e2y=u2y*r, e2z=u2z*r;
        float e3x=e1y*e2z-e1z*e2y, e3y=e1z*e2x-e1x*e2z, e3z=e1x*e2y-e1y*e2x;
        sm.rot[0]=e1x; sm.rot[1]=e2x; sm.rot[2]=e3x;
        sm.rot[3]=e1y; sm.rot[4]=e2y; sm.rot[5]=e3y;
        sm.rot[6]=e1z; sm.rot[7]=e2z; sm.rot[8]=e3z;
        sm.ca3[0]=cax; sm.ca3[1]=cay; sm.ca3[2]=caz;
    } else if (tid == 254){
        float c = 0.f;
        for (int s = 0; s < SS; ++s) c += sm.maskf[s];
        sm.cnt = c;
    }
    __syncthreads();
    if (tid < 33){
        int k = tid / 3, i2 = tid - k*3;
        sm.posall3[(A0C + k)*3 + i2] =
            sm.rot[i2*3+0]*sm.pl[k*3+0] + sm.rot[i2*3+1]*sm.pl[k*3+1] +
            sm.rot[i2*3+2]*sm.pl[k*3+2] + sm.ca3[i2];
    }
    __syncthreads();

    float pooled0 = 0.f, pooled1 = 0.f, pooled2 = 0.f, pooled3 = 0.f;

    // ====== chunk loop: fully wave-local, NO barriers inside ======
    for (int ch = 0; ch < 2; ++ch){
        const int sbase = ch * 64;

        // smolpos rows for this wave
        if (lane < 48){
            int sr = m0 + lane/3, c3 = lane - 3*(lane/3);
            sm.smolpos[sr*3 + c3] = g_spos[(n*SS + sbase + sr)*3 + c3];
        }
        // dist + invd for this wave's 16 rows (lane: row cB, atoms g*4..+4)
        {
            float px = sm.smolpos[sl*3+0], py = sm.smolpos[sl*3+1], pz = sm.smolpos[sl*3+2];
            #pragma unroll
            for (int aa = 0; aa < 4; ++aa){
                int a = g*4 + aa;
                float rx = px - sm.posall3[a*3+0];
                float ry = py - sm.posall3[a*3+1];
                float rz = pz - sm.posall3[a*3+2];
                float d  = sqrtf(rx*rx + ry*ry + rz*rz + 1e-6f);
                sm.dist[sl*17 + a] = d;
                sm.invd[sl*17 + a] = 1.0f / d;
            }
        }

        // ---- pair GEMM: dist-RBF (K=256) + dir (K=48 pad 64) ----
        f32x4 accP0 = {0.f,0.f,0.f,0.f}, accP1 = accP0, accP2 = accP0, accP3 = accP0;

        #pragma unroll 2
        for (int kk = 0; kk < 8; ++kk){
            // A-frag: 8 RBF bins of atom (2kk + lane>>5), bins ((lane>>4)&1)*8..+8, row sl.
            // All-scalar build -> one u32x4 SSA construction (no local arrays anywhere).
            float d  = sm.dist[sl*17 + 2*kk + (lane>>5)];
            float dd = d * 1.33333333f;
            float b0f = (float)(((lane>>4)&1) * 8);
            float z0 = dd - 1.06666667f*(b0f + 0.f);
            float z1 = dd - 1.06666667f*(b0f + 1.f);
            float z2 = dd - 1.06666667f*(b0f + 2.f);
            float z3 = dd - 1.06666667f*(b0f + 3.f);
            float z4 = dd - 1.06666667f*(b0f + 4.f);
            float z5 = dd - 1.06666667f*(b0f + 5.f);
            float z6 = dd - 1.06666667f*(b0f + 6.f);
            float z7 = dd - 1.06666667f*(b0f + 7.f);
            unsigned int w0 = (unsigned int)f2bf(__expf(-z0*z0)) | ((unsigned int)f2bf(__expf(-z1*z1)) << 16);
            unsigned int w1 = (unsigned int)f2bf(__expf(-z2*z2)) | ((unsigned int)f2bf(__expf(-z3*z3)) << 16);
            unsigned int w2 = (unsigned int)f2bf(__expf(-z4*z4)) | ((unsigned int)f2bf(__expf(-z5*z5)) << 16);
            unsigned int w3 = (unsigned int)f2bf(__expf(-z6*z6)) | ((unsigned int)f2bf(__expf(-z7*z7)) << 16);
            bf16x8 av = __builtin_bit_cast(bf16x8, (u32x4){w0, w1, w2, w3});

            const unsigned short* bb = wsD + cB*256 + kk*32 + g*8;
            bf16x8 B0 = *(const bf16x8*)(bb);
            bf16x8 B1 = *(const bf16x8*)(bb + 16*256);
            bf16x8 B2 = *(const bf16x8*)(bb + 32*256);
            bf16x8 B3 = *(const bf16x8*)(bb + 48*256);
            accP0 = MFMA(av, B0, accP0);
            accP1 = MFMA(av, B1, accP1);
            accP2 = MFMA(av, B2, accP2);
            accP3 = MFMA(av, B3, accP3);
        }
        #pragma unroll
        for (int kk = 0; kk < 2; ++kk){
            int k0 = kk*32 + g*8;
            unsigned int w0, w1, w2, w3;
            if (k0 < 48){
                float e0 = dirv(sm, sl, k0+0), e1 = dirv(sm, sl, k0+1);
                float e2 = dirv(sm, sl, k0+2), e3 = dirv(sm, sl, k0+3);
                float e4 = dirv(sm, sl, k0+4), e5 = dirv(sm, sl, k0+5);
                float e6 = dirv(sm, sl, k0+6), e7 = dirv(sm, sl, k0+7);
                w0 = (unsigned int)f2bf(e0) | ((unsigned int)f2bf(e1) << 16);
                w1 = (unsigned int)f2bf(e2) | ((unsigned int)f2bf(e3) << 16);
                w2 = (unsigned int)f2bf(e4) | ((unsigned int)f2bf(e5) << 16);
                w3 = (unsigned int)f2bf(e6) | ((unsigned int)f2bf(e7) << 16);
            } else {
                w0 = w1 = w2 = w3 = 0u;
            }
            bf16x8 av = __builtin_bit_cast(bf16x8, (u32x4){w0, w1, w2, w3});
            const unsigned short* bb = wsDir + cB*64 + k0;
            bf16x8 B0 = *(const bf16x8*)(bb);
            bf16x8 B1 = *(const bf16x8*)(bb + 16*64);
            bf16x8 B2 = *(const bf16x8*)(bb + 32*64);
            bf16x8 B3 = *(const bf16x8*)(bb + 48*64);
            accP0 = MFMA(av, B0, accP0);
            accP1 = MFMA(av, B1, accP1);
            accP2 = MFMA(av, B2, accP2);
            accP3 = MFMA(av, B3, accP3);
        }

        // ---- epilogue: + base + wtype, LayerNorm, direct b16 stores ----
        #pragma unroll
        for (int r = 0; r < 4; ++r){
            int slr = m0 + g*4 + r;
            int ty  = sm.typef[sbase + slr];
            float v0 = accP0[r] + sm.basev[cB +  0] + sm.wtypef[ty*PD + cB +  0];
            float v1 = accP1[r] + sm.basev[cB + 16] + sm.wtypef[ty*PD + cB + 16];
            float v2 = accP2[r] + sm.basev[cB + 32] + sm.wtypef[ty*PD + cB + 32];
            float v3 = accP3[r] + sm.basev[cB + 48] + sm.wtypef[ty*PD + cB + 48];
            float ssum = v0+v1+v2+v3;
            ssum += __shfl_xor(ssum,1); ssum += __shfl_xor(ssum,2);
            ssum += __shfl_xor(ssum,4); ssum += __shfl_xor(ssum,8);
            float mu = ssum * (1.0f/64.0f);
            float d0=v0-mu, d1=v1-mu, d2=v2-mu, d3=v3-mu;
            float sq = d0*d0+d1*d1+d2*d2+d3*d3;
            sq += __shfl_xor(sq,1); sq += __shfl_xor(sq,2);
            sq += __shfl_xor(sq,4); sq += __shfl_xor(sq,8);
            float inv = 1.0f / sqrtf(sq*(1.0f/64.0f) + 1e-5f);
            unsigned short* pr = &sm.pairT[slr*72];
            pr[cB +  0] = f2bf(d0*inv*sm.lnsc[cB +  0] + sm.lnof[cB +  0]);
            pr[cB + 16] = f2bf(d1*inv*sm.lnsc[cB + 16] + sm.lnof[cB + 16]);
            pr[cB + 32] = f2bf(d2*inv*sm.lnsc[cB + 32] + sm.lnof[cB + 32]);
            pr[cB + 48] = f2bf(d3*inv*sm.lnsc[cB + 48] + sm.lnof[cB + 48]);
        }

        // ---- MLP1 (K=64, N=128) ----
        f32x4 accH0 = {0.f,0.f,0.f,0.f}, accH1 = accH0, accH2 = accH0, accH3 = accH0,
              accH4 = accH0, accH5 = accH0, accH6 = accH0, accH7 = accH0;
        #pragma unroll
        for (int kk = 0; kk < 2; ++kk){
            bf16x8 a1 = *(const bf16x8*)&sm.pairT[(m0+cB)*72 + kk*32 + g*8];
            const unsigned short* bb = wsM1 + cB*64 + kk*32 + g*8;
            accH0 = MFMA(a1, *(const bf16x8*)(bb + 0*16*64), accH0);
            accH1 = MFMA(a1, *(const bf16x8*)(bb + 1*16*64), accH1);
            accH2 = MFMA(a1, *(const bf16x8*)(bb + 2*16*64), accH2);
            accH3 = MFMA(a1, *(const bf16x8*)(bb + 3*16*64), accH3);
            accH4 = MFMA(a1, *(const bf16x8*)(bb + 4*16*64), accH4);
            accH5 = MFMA(a1, *(const bf16x8*)(bb + 5*16*64), accH5);
            accH6 = MFMA(a1, *(const bf16x8*)(bb + 6*16*64), accH6);
            accH7 = MFMA(a1, *(const bf16x8*)(bb + 7*16*64), accH7);
        }
        // gelu + direct b16 stores
        #pragma unroll
        for (int r = 0; r < 4; ++r){
            int slr = m0 + g*4 + r;
            unsigned short* hr = &sm.hidT[slr*136];
            hr[cB + 0*16] = f2bf(gelu_f(accH0[r] + sm.b1v[cB + 0*16]));
            hr[cB + 1*16] = f2bf(gelu_f(accH1[r] + sm.b1v[cB + 1*16]));
            hr[cB + 2*16] = f2bf(gelu_f(accH2[r] + sm.b1v[cB + 2*16]));
            hr[cB + 3*16] = f2bf(gelu_f(accH3[r] + sm.b1v[cB + 3*16]));
            hr[cB + 4*16] = f2bf(gelu_f(accH4[r] + sm.b1v[cB + 4*16]));
            hr[cB + 5*16] = f2bf(gelu_f(accH5[r] + sm.b1v[cB + 5*16]));
            hr[cB + 6*16] = f2bf(gelu_f(accH6[r] + sm.b1v[cB + 6*16]));
            hr[cB + 7*16] = f2bf(gelu_f(accH7[r] + sm.b1v[cB + 7*16]));
        }

        // ---- MLP2 (K=128, N=64) + masked pooling ----
        f32x4 accO0 = {0.f,0.f,0.f,0.f}, accO1 = accO0, accO2 = accO0, accO3 = accO0;
        #pragma unroll
        for (int kk = 0; kk < 4; ++kk){
            bf16x8 a2 = *(const bf16x8*)&sm.hidT[(m0+cB)*136 + kk*32 + g*8];
            const unsigned short* bb = wsM2 + cB*128 + kk*32 + g*8;
            accO0 = MFMA(a2, *(const bf16x8*)(bb + 0*16*128), accO0);
            accO1 = MFMA(a2, *(const bf16x8*)(bb + 1*16*128), accO1);
            accO2 = MFMA(a2, *(const bf16x8*)(bb + 2*16*128), accO2);
            accO3 = MFMA(a2, *(const bf16x8*)(bb + 3*16*128), accO3);
        }
        #pragma unroll
        for (int r = 0; r < 4; ++r){
            float m = sm.maskf[sbase + m0 + g*4 + r];
            pooled0 += m * accO0[r];
            pooled1 += m * accO1[r];
            pooled2 += m * accO2[r];
            pooled3 += m * accO3[r];
        }
    } // chunk loop

    // ---- reduce pooled: across g-groups (same col), then across waves ----
    pooled0 += __shfl_xor(pooled0,16); pooled0 += __shfl_xor(pooled0,32);
    pooled1 += __shfl_xor(pooled1,16); pooled1 += __shfl_xor(pooled1,32);
    pooled2 += __shfl_xor(pooled2,16); pooled2 += __shfl_xor(pooled2,32);
    pooled3 += __shfl_xor(pooled3,16); pooled3 += __shfl_xor(pooled3,32);
    if (g == 0){
        sm.red[wv*PD + cB +  0] = pooled0;
        sm.red[wv*PD + cB + 16] = pooled1;
        sm.red[wv*PD + cB + 32] = pooled2;
        sm.red[wv*PD + cB + 48] = pooled3;
    }
    __syncthreads();
    if (tid < PD){
        float v = sm.red[tid] + sm.red[PD + tid] + sm.red[2*PD + tid] + sm.red[3*PD + tid];
        float mc = fmaxf(sm.cnt, 1.0f);
        v = (v + sm.cnt * sm.b2v[tid]) / mc;        // adds b2 exactly like ref (0 if cnt==0)
        sm.fin[tid] = sm.gatevv[tid] * v;
    }
    __syncthreads();
    {
        float a = 0.f;
        #pragma unroll 4
        for (int p = 0; p < PD; ++p) a += sm.fin[p] * w_out[p*LD + tid];
        g_out[n*LD + tid] = a;
    }
}

extern "C" void kernel_launch(void* const* d_in, const int* in_sizes, int n_in,
                              void* d_out, int out_size, void* d_ws, size_t ws_size,
                              hipStream_t stream)
{
    (void)in_sizes; (void)n_in; (void)out_size; (void)ws_size;
    const float* g_local   = (const float*)d_in[0];
    const float* g_pos     = (const float*)d_in[1];
    const int*   g_type    = (const int*)  d_in[2];
    const float* g_spos    = (const float*)d_in[3];
    const int*   g_mask    = (const int*)  d_in[4];
    const float* w_points  = (const float*)d_in[5];
    const float* w_type    = (const float*)d_in[6];
    const float* w_local   = (const float*)d_in[7];
    const float* w_dir     = (const float*)d_in[8];
    const float* w_dist    = (const float*)d_in[9];
    const float* ln_scale  = (const float*)d_in[10];
    const float* ln_offset = (const float*)d_in[11];
    const float* w_mlp1    = (const float*)d_in[12];
    const float* b_mlp1    = (const float*)d_in[13];
    const float* w_mlp2    = (const float*)d_in[14];
    const float* b_mlp2    = (const float*)d_in[15];
    const float* w_gate    = (const float*)d_in[16];
    const float* w_out     = (const float*)d_in[17];

    unsigned short* ws = (unsigned short*)d_ws;   // needs 73728 B

    smol_prep<<<dim3(144), dim3(256), 0, stream>>>(w_dist, w_dir, w_mlp1, w_mlp2, ws);

    smol_fused<<<dim3(NRES), dim3(256), 0, stream>>>(
        g_local, g_pos, g_type, g_spos, g_mask,
        w_points, w_local, w_type, ln_scale, ln_offset,
        b_mlp1, b_mlp2, w_gate, w_out, ws, (float*)d_out);
}

// Round 8
// 481.172 us; speedup vs baseline: 1.4847x; 1.0345x over previous
//
#include <hip/hip_runtime.h>
#include <math.h>

#define NRES 4096
#define SS   128
#define A0C  5
#define ATOT 16
#define LD   256
#define PD   64
#define HD   128

typedef __attribute__((ext_vector_type(8))) short bf16x8;
typedef __attribute__((ext_vector_type(4))) float f32x4;

__device__ __forceinline__ unsigned short f2bf(float x){
    unsigned int u = __builtin_bit_cast(unsigned int, x);
    unsigned int r = u + 0x7FFFu + ((u >> 16) & 1u);   // RNE to bf16
    return (unsigned short)(r >> 16);
}
__device__ __forceinline__ float gelu_f(float x){
    // x/(1+e^{-2t}), 2t = 1.59576912*(x + 0.044715 x^3)  == tanh-gelu exactly
    return x / (1.0f + __expf(-1.59576912f * x * (1.0f + 0.044715f * x * x)));
}
__device__ __forceinline__ f32x4 MFMA(bf16x8 a, bf16x8 b, f32x4 c){
    return __builtin_amdgcn_mfma_f32_16x16x32_bf16(a, b, c, 0, 0, 0);
}

// ---------------- prep: transpose+convert weights to bf16 in d_ws ----------------
// layout (ushort elements)  [identical to the passing r5 kernel]:
//   [0)      wsD   [64 n][256 k]   (w_dist^T)
//   [16384)  wsDir [64 n][64 k]    (w_dir^T, k>=48 zero)
//   [20480)  wsM1  [128 n][64 k]   (w_mlp1^T)
//   [28672)  wsM2  [64 n][128 k]   (w_mlp2^T)   total 36864 ushort = 73728 B
__global__ void smol_prep(const float* __restrict__ wdist, const float* __restrict__ wdir,
                          const float* __restrict__ wm1,  const float* __restrict__ wm2,
                          unsigned short* __restrict__ ws)
{
    int i = blockIdx.x * 256 + threadIdx.x;
    if (i < 16384){
        int nn = i >> 8, k = i & 255;
        ws[i] = f2bf(wdist[k*64 + nn]);
    } else if (i < 20480){
        int j = i - 16384; int nn = j >> 6, k = j & 63;
        ws[i] = (k < 48) ? f2bf(wdir[k*64 + nn]) : (unsigned short)0;
    } else if (i < 28672){
        int j = i - 20480; int nn = j >> 6, k = j & 63;
        ws[i] = f2bf(wm1[k*128 + nn]);
    } else if (i < 36864){
        int j = i - 28672; int nn = j >> 7, k = j & 127;
        ws[i] = f2bf(wm2[k*64 + nn]);
    }
}

// ---------------- main fused kernel ----------------
struct __align__(16) SMem {
    float  dist[64*17];             // [s][a], pad 17
    float  invd[64*17];
    unsigned short pairT[64*72];    // bf16 [s][k<=64], stride 72 (144B = 4 mod 32 words)
    unsigned short hidT[64*136];    // bf16 [s][k<=128], stride 136 (272B = 4 mod 32 words)
    float  smolpos[64*3];
    float  loc[LD];
    float  posall3[ATOT*3];
    float  pl[33];
    float  rot[9];
    float  ca3[3];
    float  wtypef[7*PD];
    float  basev[PD];
    float  gatevv[PD];
    float  lnsc[PD], lnof[PD];
    float  b1v[HD], b2v[PD];
    int    typef[SS];
    float  maskf[SS];
    float  red[4*PD];
    float  fin[PD];
    float  cnt;
};

__device__ __forceinline__ float dirv(const SMem& sm, int sl, int k){
    int a = (k * 21846) >> 16;      // k/3 for k<64
    int c = k - 3*a;
    return (sm.smolpos[sl*3+c] - sm.posall3[a*3+c]) * sm.invd[sl*17+a];
}

__global__ __launch_bounds__(256, 3)
void smol_fused(const float* __restrict__ g_local,
                const float* __restrict__ g_pos,
                const int*   __restrict__ g_type,
                const float* __restrict__ g_spos,
                const int*   __restrict__ g_mask,
                const float* __restrict__ w_points,
                const float* __restrict__ w_local,
                const float* __restrict__ w_type,
                const float* __restrict__ ln_scale,
                const float* __restrict__ ln_offset,
                const float* __restrict__ b_mlp1,
                const float* __restrict__ b_mlp2,
                const float* __restrict__ w_gate,
                const float* __restrict__ w_out,
                const unsigned short* __restrict__ ws,
                float* __restrict__ g_out)
{
    __shared__ SMem sm;
    const int n    = blockIdx.x;
    const int tid  = threadIdx.x;
    const int wv   = tid >> 6;        // wave 0..3 : owns rows 16wv..16wv+15
    const int lane = tid & 63;
    const int cB   = lane & 15;       // A-row / B-col selector
    const int g    = lane >> 4;       // k-subgroup 0..3
    const int m0   = wv * 16;
    const int sl   = m0 + cB;         // this lane's A row (chunk-local s)

    const unsigned short* wsD   = ws;
    const unsigned short* wsDir = ws + 16384;
    const unsigned short* wsM1  = ws + 20480;
    const unsigned short* wsM2  = ws + 28672;

    // ---------- stage per-n data + small weights ----------
    sm.loc[tid] = g_local[n*LD + tid];
    sm.wtypef[tid] = w_type[tid];
    if (tid < 7*PD - 256) sm.wtypef[256 + tid] = w_type[256 + tid];
    if (tid < PD){ sm.lnsc[tid] = ln_scale[tid]; sm.lnof[tid] = ln_offset[tid]; sm.b2v[tid] = b_mlp2[tid]; }
    if (tid < HD) sm.b1v[tid] = b_mlp1[tid];
    if (tid < SS){ sm.typef[tid] = g_type[n*SS + tid];
                   sm.maskf[tid] = (g_mask[n*SS + tid] != 0) ? 1.0f : 0.0f; }
    if (tid >= 128 && tid < 128 + A0C*3) sm.posall3[tid-128] = g_pos[n*A0C*3 + (tid-128)];
    __syncthreads();

    // ---------- per-n precompute ----------
    if (tid < 33){
        float a = 0.f;
        for (int i = 0; i < LD; ++i) a += sm.loc[i] * w_points[i*33 + tid];
        sm.pl[tid] = a;
    } else if (tid >= 64 && tid < 128){
        int p = tid - 64; float a = 0.f;
        for (int i = 0; i < LD; ++i) a += sm.loc[i] * w_local[i*PD + p];
        sm.basev[p] = a;
    } else if (tid >= 128 && tid < 192){
        int p = tid - 128; float a = 0.f;
        for (int i = 0; i < LD; ++i) a += sm.loc[i] * w_gate[i*PD + p];
        sm.gatevv[p] = gelu_f(a);
    } else if (tid == 255){
        float nx=sm.posall3[0], ny=sm.posall3[1], nz=sm.posall3[2];
        float cax=sm.posall3[3], cay=sm.posall3[4], caz=sm.posall3[5];
        float cx=sm.posall3[6], cy=sm.posall3[7], cz=sm.posall3[8];
        float v1x=cx-cax, v1y=cy-cay, v1z=cz-caz;
        float r = 1.0f/sqrtf(v1x*v1x + v1y*v1y + v1z*v1z + 1e-6f);
        float e1x=v1x*r, e1y=v1y*r, e1z=v1z*r;
        float v2x=nx-cax, v2y=ny-cay, v2z=nz-caz;
        float dp = e1x*v2x + e1y*v2y + e1z*v2z;
        float u2x=v2x-e1x*dp, u2y=v2y-e1y*dp, u2z=v2z-e1z*dp;
        r = 1.0f/sqrtf(u2x*u2x + u2y*u2y + u2z*u2z + 1e-6f);
        float e2x=u2x*r, e2y=u2y*r, e2z=u2z*r;
        float e3x=e1y*e2z-e1z*e2y, e3y=e1z*e2x-e1x*e2z, e3z=e1x*e2y-e1y*e2x;
        sm.rot[0]=e1x; sm.rot[1]=e2x; sm.rot[2]=e3x;
        sm.rot[3]=e1y; sm.rot[4]=e2y; sm.rot[5]=e3y;
        sm.rot[6]=e1z; sm.rot[7]=e2z; sm.rot[8]=e3z;
        sm.ca3[0]=cax; sm.ca3[1]=cay; sm.ca3[2]=caz;
    } else if (tid == 254){
        float c = 0.f;
        for (int s = 0; s < SS; ++s) c += sm.maskf[s];
        sm.cnt = c;
    }
    __syncthreads();
    if (tid < 33){
        int k = tid / 3, i2 = tid - k*3;
        sm.posall3[(A0C + k)*3 + i2] =
            sm.rot[i2*3+0]*sm.pl[k*3+0] + sm.rot[i2*3+1]*sm.pl[k*3+1] +
            sm.rot[i2*3+2]*sm.pl[k*3+2] + sm.ca3[i2];
    }
    __syncthreads();

    float pooled0 = 0.f, pooled1 = 0.f, pooled2 = 0.f, pooled3 = 0.f;

    // ====== chunk loop: fully wave-local, NO barriers inside (r5 structure) ======
    for (int ch = 0; ch < 2; ++ch){
        const int sbase = ch * 64;

        // smolpos rows for this wave
        if (lane < 48){
            int sr = m0 + lane/3, c3 = lane - 3*(lane/3);
            sm.smolpos[sr*3 + c3] = g_spos[(n*SS + sbase + sr)*3 + c3];
        }
        // dist + invd for this wave's 16 rows (lane: row cB, atoms g*4..+4)
        {
            float px = sm.smolpos[sl*3+0], py = sm.smolpos[sl*3+1], pz = sm.smolpos[sl*3+2];
            #pragma unroll
            for (int aa = 0; aa < 4; ++aa){
                int a = g*4 + aa;
                float rx = px - sm.posall3[a*3+0];
                float ry = py - sm.posall3[a*3+1];
                float rz = pz - sm.posall3[a*3+2];
                float d  = sqrtf(rx*rx + ry*ry + rz*rz + 1e-6f);
                sm.dist[sl*17 + a] = d;
                sm.invd[sl*17 + a] = 1.0f / d;
            }
        }

        // ---- pair GEMM: dist-RBF (K=256) + dir (K=48 pad 64) ----
        f32x4 accP0 = {0.f,0.f,0.f,0.f}, accP1 = accP0, accP2 = accP0, accP3 = accP0;

        #pragma unroll 2
        for (int kk = 0; kk < 8; ++kk){
            // A-frag: 8 RBF bins of atom (2kk + g>>1), bins (g&1)*8..+8, row sl.
            // r8: direct constant-index element inserts (no u32x4 literal / bit_cast).
            float d  = sm.dist[sl*17 + 2*kk + (g>>1)];
            float dd = d * 1.33333333f;
            float b0f = (float)((g&1) * 8);
            float z0 = dd - 1.06666667f*(b0f + 0.f);
            float z1 = dd - 1.06666667f*(b0f + 1.f);
            float z2 = dd - 1.06666667f*(b0f + 2.f);
            float z3 = dd - 1.06666667f*(b0f + 3.f);
            float z4 = dd - 1.06666667f*(b0f + 4.f);
            float z5 = dd - 1.06666667f*(b0f + 5.f);
            float z6 = dd - 1.06666667f*(b0f + 6.f);
            float z7 = dd - 1.06666667f*(b0f + 7.f);
            bf16x8 av;
            av[0] = (short)f2bf(__expf(-z0*z0));
            av[1] = (short)f2bf(__expf(-z1*z1));
            av[2] = (short)f2bf(__expf(-z2*z2));
            av[3] = (short)f2bf(__expf(-z3*z3));
            av[4] = (short)f2bf(__expf(-z4*z4));
            av[5] = (short)f2bf(__expf(-z5*z5));
            av[6] = (short)f2bf(__expf(-z6*z6));
            av[7] = (short)f2bf(__expf(-z7*z7));

            const unsigned short* bb = wsD + cB*256 + kk*32 + g*8;
            accP0 = MFMA(av, *(const bf16x8*)(bb),          accP0);
            accP1 = MFMA(av, *(const bf16x8*)(bb + 16*256), accP1);
            accP2 = MFMA(av, *(const bf16x8*)(bb + 32*256), accP2);
            accP3 = MFMA(av, *(const bf16x8*)(bb + 48*256), accP3);
        }
        #pragma unroll
        for (int kk = 0; kk < 2; ++kk){
            int k0 = kk*32 + g*8;
            bf16x8 av;
            if (k0 < 48){
                av[0] = (short)f2bf(dirv(sm, sl, k0+0));
                av[1] = (short)f2bf(dirv(sm, sl, k0+1));
                av[2] = (short)f2bf(dirv(sm, sl, k0+2));
                av[3] = (short)f2bf(dirv(sm, sl, k0+3));
                av[4] = (short)f2bf(dirv(sm, sl, k0+4));
                av[5] = (short)f2bf(dirv(sm, sl, k0+5));
                av[6] = (short)f2bf(dirv(sm, sl, k0+6));
                av[7] = (short)f2bf(dirv(sm, sl, k0+7));
            } else {
                av[0]=0; av[1]=0; av[2]=0; av[3]=0; av[4]=0; av[5]=0; av[6]=0; av[7]=0;
            }
            const unsigned short* bb = wsDir + cB*64 + k0;
            accP0 = MFMA(av, *(const bf16x8*)(bb),         accP0);
            accP1 = MFMA(av, *(const bf16x8*)(bb + 16*64), accP1);
            accP2 = MFMA(av, *(const bf16x8*)(bb + 32*64), accP2);
            accP3 = MFMA(av, *(const bf16x8*)(bb + 48*64), accP3);
        }

        // ---- epilogue: + base + wtype, LayerNorm, direct b16 stores ----
        #pragma unroll
        for (int r = 0; r < 4; ++r){
            int slr = m0 + g*4 + r;
            int ty  = sm.typef[sbase + slr];
            float v0 = accP0[r] + sm.basev[cB +  0] + sm.wtypef[ty*PD + cB +  0];
            float v1 = accP1[r] + sm.basev[cB + 16] + sm.wtypef[ty*PD + cB + 16];
            float v2 = accP2[r] + sm.basev[cB + 32] + sm.wtypef[ty*PD + cB + 32];
            float v3 = accP3[r] + sm.basev[cB + 48] + sm.wtypef[ty*PD + cB + 48];
            float ssum = v0+v1+v2+v3;
            ssum += __shfl_xor(ssum,1); ssum += __shfl_xor(ssum,2);
            ssum += __shfl_xor(ssum,4); ssum += __shfl_xor(ssum,8);
            float mu = ssum * (1.0f/64.0f);
            float d0=v0-mu, d1=v1-mu, d2=v2-mu, d3=v3-mu;
            float sq = d0*d0+d1*d1+d2*d2+d3*d3;
            sq += __shfl_xor(sq,1); sq += __shfl_xor(sq,2);
            sq += __shfl_xor(sq,4); sq += __shfl_xor(sq,8);
            float inv = 1.0f / sqrtf(sq*(1.0f/64.0f) + 1e-5f);
            unsigned short* pr = &sm.pairT[slr*72];
            pr[cB +  0] = f2bf(d0*inv*sm.lnsc[cB +  0] + sm.lnof[cB +  0]);
            pr[cB + 16] = f2bf(d1*inv*sm.lnsc[cB + 16] + sm.lnof[cB + 16]);
            pr[cB + 32] = f2bf(d2*inv*sm.lnsc[cB + 32] + sm.lnof[cB + 32]);
            pr[cB + 48] = f2bf(d3*inv*sm.lnsc[cB + 48] + sm.lnof[cB + 48]);
        }

        // ---- MLP1 (K=64, N=128) ----
        f32x4 accH0 = {0.f,0.f,0.f,0.f}, accH1 = accH0, accH2 = accH0, accH3 = accH0,
              accH4 = accH0, accH5 = accH0, accH6 = accH0, accH7 = accH0;
        #pragma unroll
        for (int kk = 0; kk < 2; ++kk){
            bf16x8 a1 = *(const bf16x8*)&sm.pairT[(m0+cB)*72 + kk*32 + g*8];
            const unsigned short* bb = wsM1 + cB*64 + kk*32 + g*8;
            accH0 = MFMA(a1, *(const bf16x8*)(bb + 0*16*64), accH0);
            accH1 = MFMA(a1, *(const bf16x8*)(bb + 1*16*64), accH1);
            accH2 = MFMA(a1, *(const bf16x8*)(bb + 2*16*64), accH2);
            accH3 = MFMA(a1, *(const bf16x8*)(bb + 3*16*64), accH3);
            accH4 = MFMA(a1, *(const bf16x8*)(bb + 4*16*64), accH4);
            accH5 = MFMA(a1, *(const bf16x8*)(bb + 5*16*64), accH5);
            accH6 = MFMA(a1, *(const bf16x8*)(bb + 6*16*64), accH6);
            accH7 = MFMA(a1, *(const bf16x8*)(bb + 7*16*64), accH7);
        }
        // gelu + direct b16 stores
        #pragma unroll
        for (int r = 0; r < 4; ++r){
            int slr = m0 + g*4 + r;
            unsigned short* hr = &sm.hidT[slr*136];
            hr[cB + 0*16] = f2bf(gelu_f(accH0[r] + sm.b1v[cB + 0*16]));
            hr[cB + 1*16] = f2bf(gelu_f(accH1[r] + sm.b1v[cB + 1*16]));
            hr[cB + 2*16] = f2bf(gelu_f(accH2[r] + sm.b1v[cB + 2*16]));
            hr[cB + 3*16] = f2bf(gelu_f(accH3[r] + sm.b1v[cB + 3*16]));
            hr[cB + 4*16] = f2bf(gelu_f(accH4[r] + sm.b1v[cB + 4*16]));
            hr[cB + 5*16] = f2bf(gelu_f(accH5[r] + sm.b1v[cB + 5*16]));
            hr[cB + 6*16] = f2bf(gelu_f(accH6[r] + sm.b1v[cB + 6*16]));
            hr[cB + 7*16] = f2bf(gelu_f(accH7[r] + sm.b1v[cB + 7*16]));
        }

        // ---- MLP2 (K=128, N=64) + masked pooling ----
        f32x4 accO0 = {0.f,0.f,0.f,0.f}, accO1 = accO0, accO2 = accO0, accO3 = accO0;
        #pragma unroll
        for (int kk = 0; kk < 4; ++kk){
            bf16x8 a2 = *(const bf16x8*)&sm.hidT[(m0+cB)*136 + kk*32 + g*8];
            const unsigned short* bb = wsM2 + cB*128 + kk*32 + g*8;
            accO0 = MFMA(a2, *(const bf16x8*)(bb + 0*16*128), accO0);
            accO1 = MFMA(a2, *(const bf16x8*)(bb + 1*16*128), accO1);
            accO2 = MFMA(a2, *(const bf16x8*)(bb + 2*16*128), accO2);
            accO3 = MFMA(a2, *(const bf16x8*)(bb + 3*16*128), accO3);
        }
        #pragma unroll
        for (int r = 0; r < 4; ++r){
            float m = sm.maskf[sbase + m0 + g*4 + r];
            pooled0 += m * accO0[r];
            pooled1 += m * accO1[r];
            pooled2 += m * accO2[r];
            pooled3 += m * accO3[r];
        }
    } // chunk loop

    // ---- reduce pooled: across g-groups (same col), then across waves ----
    pooled0 += __shfl_xor(pooled0,16); pooled0 += __shfl_xor(pooled0,32);
    pooled1 += __shfl_xor(pooled1,16); pooled1 += __shfl_xor(pooled1,32);
    pooled2 += __shfl_xor(pooled2,16); pooled2 += __shfl_xor(pooled2,32);
    pooled3 += __shfl_xor(pooled3,16); pooled3 += __shfl_xor(pooled3,32);
    if (g == 0){
        sm.red[wv*PD + cB +  0] = pooled0;
        sm.red[wv*PD + cB + 16] = pooled1;
        sm.red[wv*PD + cB + 32] = pooled2;
        sm.red[wv*PD + cB + 48] = pooled3;
    }
    __syncthreads();
    if (tid < PD){
        float v = sm.red[tid] + sm.red[PD + tid] + sm.red[2*PD + tid] + sm.red[3*PD + tid];
        float mc = fmaxf(sm.cnt, 1.0f);
        v = (v + sm.cnt * sm.b2v[tid]) / mc;        // adds b2 exactly like ref (0 if cnt==0)
        sm.fin[tid] = sm.gatevv[tid] * v;
    }
    __syncthreads();
    {
        float a = 0.f;
        #pragma unroll 4
        for (int p = 0; p < PD; ++p) a += sm.fin[p] * w_out[p*LD + tid];
        g_out[n*LD + tid] = a;
    }
}

extern "C" void kernel_launch(void* const* d_in, const int* in_sizes, int n_in,
                              void* d_out, int out_size, void* d_ws, size_t ws_size,
                              hipStream_t stream)
{
    (void)in_sizes; (void)n_in; (void)out_size; (void)ws_size;
    const float* g_local   = (const float*)d_in[0];
    const float* g_pos     = (const float*)d_in[1];
    const int*   g_type    = (const int*)  d_in[2];
    const float* g_spos    = (const float*)d_in[3];
    const int*   g_mask    = (const int*)  d_in[4];
    const float* w_points  = (const float*)d_in[5];
    const float* w_type    = (const float*)d_in[6];
    const float* w_local   = (const float*)d_in[7];
    const float* w_dir     = (const float*)d_in[8];
    const float* w_dist    = (const float*)d_in[9];
    const float* ln_scale  = (const float*)d_in[10];
    const float* ln_offset = (const float*)d_in[11];
    const float* w_mlp1    = (const float*)d_in[12];
    const float* b_mlp1    = (const float*)d_in[13];
    const float* w_mlp2    = (const float*)d_in[14];
    const float* b_mlp2    = (const float*)d_in[15];
    const float* w_gate    = (const float*)d_in[16];
    const float* w_out     = (const float*)d_in[17];

    unsigned short* ws = (unsigned short*)d_ws;   // needs 73728 B

    smol_prep<<<dim3(144), dim3(256), 0, stream>>>(w_dist, w_dir, w_mlp1, w_mlp2, ws);

    smol_fused<<<dim3(NRES), dim3(256), 0, stream>>>(
        g_local, g_pos, g_type, g_spos, g_mask,
        w_points, w_local, w_type, ln_scale, ln_offset,
        b_mlp1, b_mlp2, w_gate, w_out, ws, (float*)d_out);
}